// Round 12
// baseline (537.415 us; speedup 1.0000x reference)
//
#include <hip/hip_runtime.h>
#include <math.h>

typedef __attribute__((ext_vector_type(8))) short bf16x8;
typedef __attribute__((ext_vector_type(4))) float f32x4;

__device__ __forceinline__ unsigned short f2bf(float f) {
  unsigned int u = __float_as_uint(f);
  unsigned int r = (u + 0x7fffu + ((u >> 16) & 1u)) >> 16;
  return (unsigned short)r;
}
__device__ __forceinline__ unsigned int pack2bf(float a, float b) {
  return (unsigned int)f2bf(a) | ((unsigned int)f2bf(b) << 16);
}
__device__ __forceinline__ float bflo(unsigned int g) { return __uint_as_float(g << 16); }
__device__ __forceinline__ float bfhi(unsigned int g) { return __uint_as_float(g & 0xffff0000u); }

__device__ __forceinline__ void glds16(const void* gp, void* lp) {
  __builtin_amdgcn_global_load_lds(
      (const __attribute__((address_space(1))) void*)gp,
      (__attribute__((address_space(3))) void*)lp, 16, 0, 0);
}

// cos/sin(pi*j/16), j=0..15 — cover all in-lane FFT32 twiddles
__device__ __constant__ float CW16[16] = {
  1.0f, 0.9807852804032304f, 0.9238795325112867f, 0.8314696123025452f,
  0.7071067811865476f, 0.5555702330196022f, 0.3826834323650898f, 0.19509032201612828f,
  0.0f, -0.19509032201612828f, -0.3826834323650898f, -0.5555702330196022f,
  -0.7071067811865476f, -0.8314696123025452f, -0.9238795325112867f, -0.9807852804032304f};
__device__ __constant__ float SW16[16] = {
  0.0f, 0.19509032201612828f, 0.3826834323650898f, 0.5555702330196022f,
  0.7071067811865476f, 0.8314696123025452f, 0.9238795325112867f, 0.9807852804032304f,
  1.0f, 0.9807852804032304f, 0.9238795325112867f, 0.8314696123025452f,
  0.7071067811865476f, 0.5555702330196022f, 0.3826834323650898f, 0.19509032201612828f};
__device__ __constant__ int BR5[32] = {
  0,16,8,24,4,20,12,28,2,18,10,26,6,22,14,30,
  1,17,9,25,5,21,13,29,3,19,11,27,7,23,15,31};

__device__ __forceinline__ int bitrev6(int l) {
  return ((l&1)<<5)|((l&2)<<3)|((l&4)<<1)|((l&8)>>1)|((l&16)>>3)|((l&32)>>5);
}

// hardware sin/cos: input in REVOLUTIONS (angle/2pi); all our args are in [0,1)
__device__ __forceinline__ float hsin(float rev) { return __builtin_amdgcn_sinf(rev); }
__device__ __forceinline__ float hcos(float rev) { return __builtin_amdgcn_cosf(rev); }

#define STAGE_FENCE() __builtin_amdgcn_sched_barrier(0)

// ---------- forward half: cross-lane DIF-64, mid-twiddle, in-lane DIF-32 ----------
// Entry: ur/ui[j] = z[n = 32*lane + j]. Exit: reg p, lane l hold Z[k],
// k = bitrev6(l) + 64*bitrev5(p). Branchless butterflies (R8-verified).
// STAGE_FENCE after every stage caps scheduler-induced register pressure at
// ~64 state + ~16 temps — R10's 206 MB spill at the 128-VGPR cap came from
// cross-stage interleaving creating concurrent live ranges.
__device__ __forceinline__ void fwd_core(float (&ur)[32], float (&ui)[32], const int lane) {
  #pragma unroll
  for (int s = 0; s < 6; ++s) {
    const int h = 32 >> s;
    const int j = lane & (h - 1);
    const float rev = (float)j * (0.5f / (float)h);   // angle = pi*j/h
    const bool hi = (lane & h) != 0;
    const float c  = hi ? hcos(rev) : 1.0f;           // w_eff = c - i*s (lo: identity)
    const float sv = hi ? hsin(rev) : 0.0f;
    const float sgn = hi ? -1.0f : 1.0f;
    #pragma unroll
    for (int r = 0; r < 32; ++r) {
      float pr = __shfl_xor(ur[r], h, 64);
      float pi = __shfl_xor(ui[r], h, 64);
      float tr = fmaf(sgn, ur[r], pr);   // lo: self+partner ; hi: partner-self
      float ti = fmaf(sgn, ui[r], pi);
      ur[r] = fmaf(ti, sv, tr * c);      // (tr + i*ti) * (c - i*sv)
      ui[r] = fmaf(-tr, sv, ti * c);
    }
    STAGE_FENCE();
  }
  const int kap = bitrev6(lane);
  #pragma unroll
  for (int j = 1; j < 32; ++j) {
    const float rev = (float)(j * kap) * (1.0f / 2048.0f);
    const float sn = hsin(rev), cs = hcos(rev);
    float t = ur[j] * cs + ui[j] * sn;
    ui[j] = ui[j] * cs - ur[j] * sn;
    ur[j] = t;
  }
  STAGE_FENCE();
  #pragma unroll
  for (int s = 0; s < 5; ++s) {
    const int h = 16 >> s;
    #pragma unroll
    for (int i = 0; i < 32; ++i) if (!(i & h)) {
      const int tw = (i & (h - 1)) * (16 / h);
      float dr = ur[i] - ur[i + h], di = ui[i] - ui[i + h];
      ur[i] += ur[i + h]; ui[i] += ui[i + h];
      ur[i + h] = dr * CW16[tw] + di * SW16[tw];
      ui[i + h] = di * CW16[tw] - dr * SW16[tw];
    }
    STAGE_FENCE();
  }
}

// ---------- inverse half: in-lane DIT-32, inv mid-twiddle, cross-lane DIT-64 ----------
__device__ __forceinline__ void inv_core(float (&ur)[32], float (&ui)[32], const int lane) {
  const int kap = bitrev6(lane);
  #pragma unroll
  for (int s = 0; s < 5; ++s) {
    const int h = 1 << s;
    #pragma unroll
    for (int i = 0; i < 32; ++i) if (!(i & h)) {
      const int tw = (i & (h - 1)) * (16 / h);
      float tr2 = ur[i + h] * CW16[tw] - ui[i + h] * SW16[tw];
      float ti2 = ui[i + h] * CW16[tw] + ur[i + h] * SW16[tw];
      ur[i + h] = ur[i] - tr2; ui[i + h] = ui[i] - ti2;
      ur[i] += tr2; ui[i] += ti2;
    }
    STAGE_FENCE();
  }
  #pragma unroll
  for (int j = 1; j < 32; ++j) {
    const float rev = (float)(j * kap) * (1.0f / 2048.0f);
    const float sn = hsin(rev), cs = hcos(rev);
    float t = ur[j] * cs - ui[j] * sn;
    ui[j] = ui[j] * cs + ur[j] * sn;
    ur[j] = t;
  }
  STAGE_FENCE();
  // branchless DIT: premultiply own value by w_eff (lo: identity), swap, +-.
  #pragma unroll
  for (int s = 0; s < 6; ++s) {
    const int h = 1 << s;
    const int j = lane & (h - 1);
    const float rev = (float)j * (0.5f / (float)h);
    const bool hi = (lane & h) != 0;
    const float c  = hi ? hcos(rev) : 1.0f;           // w_eff = c + i*s
    const float sv = hi ? hsin(rev) : 0.0f;
    const float sgn = hi ? -1.0f : 1.0f;
    #pragma unroll
    for (int r = 0; r < 32; ++r) {
      float vr = fmaf(-ui[r], sv, ur[r] * c);   // v = self * w_eff
      float vi = fmaf(ur[r], sv, ui[r] * c);
      float pvr = __shfl_xor(vr, h, 64);
      float pvi = __shfl_xor(vi, h, 64);
      ur[r] = fmaf(sgn, vr, pvr);   // lo: v+pv ; hi: pv-v
      ui[r] = fmaf(sgn, vi, pvi);
    }
    STAGE_FENCE();
  }
}

// ---------- gate transpose + Hermitian extend + pack (fallback path) ----------
__global__ __launch_bounds__(256) void gate_pack_k(const float* __restrict__ gr,
                                                   const float* __restrict__ gi,
                                                   unsigned int* __restrict__ gt) {
  __shared__ float tr[32][33];
  __shared__ float ti[32][33];
  const int t = threadIdx.x;
  const int k0 = blockIdx.x * 32, hb = blockIdx.y * 32;
  const int hx = t & 31, fr = t >> 5;
  #pragma unroll
  for (int p = 0; p < 4; ++p) {
    int ff = p * 8 + fr;
    int k = k0 + ff;
    int f = (k <= 1024) ? k : (2048 - k);
    float sg = (k <= 1024) ? 1.f : -1.f;
    tr[ff][hx] = gr[(size_t)f * 2048 + hb + hx] * (1.f / 2048.f);
    ti[ff][hx] = sg * gi[(size_t)f * 2048 + hb + hx] * (1.f / 2048.f);
  }
  __syncthreads();
  const int kk = t & 31, hr = t >> 5;
  #pragma unroll
  for (int p = 0; p < 4; ++p) {
    int hl = p * 8 + hr;
    float re = tr[kk][hl], im = ti[kk][hl];
    gt[(size_t)(hb + hl) * 2048 + k0 + kk] =
        (unsigned int)f2bf(re) | ((unsigned int)f2bf(im) << 16);
  }
}

// ---------- pair-gate table: P,Q = (G[2j] +- G[2j+1]) * 0.5 / 2048, bf16x4 ----------
__global__ __launch_bounds__(256) void gate_pair_k(const float* __restrict__ gr,
                                                   const float* __restrict__ gi,
                                                   uint2* __restrict__ pq) {
  __shared__ float tr[32][65];
  __shared__ float ti[32][65];
  const int t = threadIdx.x;
  const int k0 = blockIdx.x * 32;   // k tile
  const int p0 = blockIdx.y * 32;   // pair tile (h base = 2*p0)
  const int hb = p0 * 2;
  const int hx = t & 63, fr = t >> 6;
  #pragma unroll
  for (int pp = 0; pp < 8; ++pp) {
    int ff = pp * 4 + fr;
    int k = k0 + ff;
    int f = (k <= 1024) ? k : (2048 - k);
    float sg = (k <= 1024) ? 1.f : -1.f;
    tr[ff][hx] = gr[(size_t)f * 2048 + hb + hx] * (1.f / 2048.f);
    ti[ff][hx] = sg * gi[(size_t)f * 2048 + hb + hx] * (1.f / 2048.f);
  }
  __syncthreads();
  const int kk = t & 31, jr = t >> 5;
  #pragma unroll
  for (int pp = 0; pp < 4; ++pp) {
    int jj = pp * 8 + jr;
    float gar = tr[kk][2 * jj],     gai = ti[kk][2 * jj];
    float gbr = tr[kk][2 * jj + 1], gbi = ti[kk][2 * jj + 1];
    float Pr = (gar + gbr) * 0.5f, Pi = (gai + gbi) * 0.5f;
    float Qr = (gar - gbr) * 0.5f, Qi = (gai - gbi) * 0.5f;
    uint2 v;
    v.x = (unsigned int)f2bf(Pr) | ((unsigned int)f2bf(Pi) << 16);
    v.y = (unsigned int)f2bf(Qr) | ((unsigned int)f2bf(Qi) << 16);
    pq[(size_t)(p0 + jj) * 2048 + k0 + kk] = v;
  }
}

// ---------- W f32 -> bf16 ----------
__global__ __launch_bounds__(256) void wconv_k(const float* __restrict__ W,
                                               unsigned short* __restrict__ Wb) {
  int i = blockIdx.x * 256 + threadIdx.x;
  float4 v = ((const float4*)W)[i];
  ushort4 o;
  o.x = f2bf(v.x); o.y = f2bf(v.y); o.z = f2bf(v.z); o.w = f2bf(v.w);
  ((ushort4*)Wb)[i] = o;
}

// ---------- T1: x [b,s,h] -> xT [b,h,s], f32 32x32 tiles ----------
__global__ __launch_bounds__(256) void xtrans_k(const float* __restrict__ x,
                                                float* __restrict__ xT) {
  __shared__ float t[32][33];
  const int b = blockIdx.z;
  const int s0 = blockIdx.x * 32, h0 = blockIdx.y * 32;
  const float* xb = x + ((size_t)b * 2048) * 2048;
  float* xTb = xT + ((size_t)b * 2048) * 2048;
  const int c = threadIdx.x & 31, r = threadIdx.x >> 5;
  #pragma unroll
  for (int p = 0; p < 4; ++p) {
    int rr = p * 8 + r;
    t[rr][c] = xb[(size_t)(s0 + rr) * 2048 + h0 + c];
  }
  __syncthreads();
  #pragma unroll
  for (int p = 0; p < 4; ++p) {
    int rr = p * 8 + r;
    xTb[(size_t)(h0 + rr) * 2048 + s0 + c] = t[c][rr];
  }
}

// ---------- T2: yT [b,h,s] -> y [b,s,h], bf16 64x64 tiles ----------
__global__ __launch_bounds__(256) void ytrans_k(const unsigned short* __restrict__ yT,
                                                unsigned short* __restrict__ y) {
  __shared__ unsigned short t[64][66];
  const int b = blockIdx.z;
  const int h0 = blockIdx.x * 64, s0 = blockIdx.y * 64;
  const unsigned short* src = yT + ((size_t)b * 2048 + h0) * 2048 + s0;
  unsigned short* dst = y + ((size_t)b * 2048 + s0) * 2048 + h0;
  const int c = threadIdx.x & 15, r = threadIdx.x >> 4;
  #pragma unroll
  for (int p = 0; p < 4; ++p) {
    int rr = p * 16 + r;
    ushort4 v = *(const ushort4*)(src + (size_t)rr * 2048 + c * 4);
    *(ushort4*)&t[rr][c * 4] = v;
  }
  __syncthreads();
  #pragma unroll
  for (int p = 0; p < 4; ++p) {
    int rr = p * 16 + r;
    ushort4 o;
    o.x = t[c * 4 + 0][rr]; o.y = t[c * 4 + 1][rr];
    o.z = t[c * 4 + 2][rr]; o.w = t[c * 4 + 3][rr];
    *(ushort4*)(dst + (size_t)rr * 2048 + c * 4) = o;
  }
}

// ---------- pair FFT: z = x[2j] + i*x[2j+1]; Z' = P*Z + Q*conj(rev Z); IFFT ----------
// Partner of k = kap + 64*m (m=bitrev5(p)) is at lane bitrev6(64-kap), reg 31-p.
// Lane 0 (kap=0) partners itself with reg perm P0L (self-closed) — via LDS snapshot.
// Composition of proven pieces: R6/R9 allocator config (flat_wgs 256 +
// waves_per_eu(2,4) -> VGPR 128, 4-wave granule), R7 chunked gate loop (kills
// gate-load hoist spill), R7 direct stores (WRITE ideal; obuf dropped ->
// 1 KB LDS, no bank conflicts), NEW per-stage STAGE_FENCEs in the cores.
__global__ __attribute__((amdgpu_flat_work_group_size(256, 256)))
__attribute__((amdgpu_waves_per_eu(2, 4)))
void fftp_k(const float* __restrict__ xT,
            const uint2* __restrict__ pq,
            unsigned short* __restrict__ yT) {
  __shared__ float snap[4][64];
  const int tid = threadIdx.x;
  const int w = tid >> 6, lane = tid & 63;
  const int pid = blockIdx.x * 4 + w;     // pair id, 0..8191
  const int b = pid >> 10, j = pid & 1023;
  const size_t col_a = ((size_t)b * 2048 + 2 * j) * 2048;

  float ur[32], ui[32];
  const float4* xa = (const float4*)(xT + col_a);
  const float4* xb = (const float4*)(xT + col_a + 2048);
  #pragma unroll
  for (int q = 0; q < 8; ++q) {
    float4 va = xa[lane * 8 + q];
    float4 vb = xb[lane * 8 + q];
    ur[q * 4 + 0] = va.x; ur[q * 4 + 1] = va.y; ur[q * 4 + 2] = va.z; ur[q * 4 + 3] = va.w;
    ui[q * 4 + 0] = vb.x; ui[q * 4 + 1] = vb.y; ui[q * 4 + 2] = vb.z; ui[q * 4 + 3] = vb.w;
  }

  fwd_core(ur, ui, lane);

  // lane-0 snapshot (its conj-partners are its own regs, perm P0L); wave-local,
  // DS pipe in-order -> no barrier needed before the reads below.
  if (lane == 0) {
    #pragma unroll
    for (int p = 0; p < 32; ++p) { snap[w][2 * p] = ur[p]; snap[w][2 * p + 1] = ui[p]; }
  }

  const int kap = bitrev6(lane);
  const int lsrc = bitrev6((64 - kap) & 63);
  const uint2* pqrow = pq + (size_t)j * 2048;
  constexpr int P0L[32] = {0,1,3,2,7,6,5,4,15,14,13,12,11,10,9,8,
                           31,30,29,28,27,26,25,24,23,22,21,20,19,18,17,16};
  const bool l0 = (lane == 0);
  #pragma unroll
  for (int c4 = 0; c4 < 4; ++c4) {
    STAGE_FENCE();   // cap load-hoisting to one chunk (R7-proven)
    #pragma unroll
    for (int pp = 0; pp < 4; ++pp) {
      const int p = c4 * 4 + pp;
      const int pb = 31 - p;
      // gather conj-partners for regs p and pb (before overwriting either)
      float arp = __shfl(ur[pb], lsrc), aip = __shfl(ui[pb], lsrc);
      float arq = __shfl(ur[p], lsrc),  aiq = __shfl(ui[p], lsrc);
      float s0r = snap[w][2 * P0L[p]],  s0i = snap[w][2 * P0L[p] + 1];
      float s1r = snap[w][2 * P0L[pb]], s1i = snap[w][2 * P0L[pb] + 1];
      arp = l0 ? s0r : arp;  aip = l0 ? s0i : aip;
      arq = l0 ? s1r : arq;  aiq = l0 ? s1i : aiq;
      uint2 gp = pqrow[(BR5[p] << 6) + kap];
      uint2 gq = pqrow[(BR5[pb] << 6) + kap];
      {
        float Pr = bflo(gp.x), Pi = bfhi(gp.x), Qr = bflo(gp.y), Qi = bfhi(gp.y);
        float zr = ur[p], zi = ui[p];
        ur[p] = Pr * zr - Pi * zi + Qr * arp + Qi * aip;
        ui[p] = Pr * zi + Pi * zr + Qi * arp - Qr * aip;
      }
      {
        float Pr = bflo(gq.x), Pi = bfhi(gq.x), Qr = bflo(gq.y), Qi = bfhi(gq.y);
        float zr = ur[pb], zi = ui[pb];
        ur[pb] = Pr * zr - Pi * zi + Qr * arq + Qi * aiq;
        ui[pb] = Pr * zi + Pi * zr + Qi * arq - Qr * aiq;
      }
    }
  }
  STAGE_FENCE();

  inv_core(ur, ui, lane);

  // ---- store: lane's 32 elements are contiguous 64B at n=32*lane; the wave's
  // 4 store instructions tile a contiguous 4KB column (R7: WRITE_SIZE ideal).
  uint4* dsta = (uint4*)(yT + col_a) + lane * 4;
  #pragma unroll
  for (int q = 0; q < 4; ++q) {
    uint4 o;
    o.x = pack2bf(ur[q * 8 + 0], ur[q * 8 + 1]);
    o.y = pack2bf(ur[q * 8 + 2], ur[q * 8 + 3]);
    o.z = pack2bf(ur[q * 8 + 4], ur[q * 8 + 5]);
    o.w = pack2bf(ur[q * 8 + 6], ur[q * 8 + 7]);
    dsta[q] = o;
  }
  uint4* dstb = (uint4*)(yT + col_a + 2048) + lane * 4;
  #pragma unroll
  for (int q = 0; q < 4; ++q) {
    uint4 o;
    o.x = pack2bf(ui[q * 8 + 0], ui[q * 8 + 1]);
    o.y = pack2bf(ui[q * 8 + 2], ui[q * 8 + 3]);
    o.z = pack2bf(ui[q * 8 + 4], ui[q * 8 + 5]);
    o.w = pack2bf(ui[q * 8 + 6], ui[q * 8 + 7]);
    dstb[q] = o;
  }
}

// ---------- fallback (R3-proven): FFT reading x directly via LDS staging ----------
__global__ __attribute__((amdgpu_flat_work_group_size(512, 512)))
__attribute__((amdgpu_waves_per_eu(2, 4)))
void fft_gate_k(const float* __restrict__ x,
                const unsigned int* __restrict__ gt,
                unsigned short* __restrict__ y) {
  __shared__ float lds[8 * 516];
  const int tid = threadIdx.x;
  const int w = tid >> 6;
  const int lane = tid & 63;
  const int bid = blockIdx.x;
  const int swz = (bid & 7) * 256 + (bid >> 3);
  const int h0 = (swz & 255) << 3;
  const int b = swz >> 8;
  const int hh = tid & 7, srow = tid >> 3;

  float ur[32], ui[32];
  const size_t xbase = ((size_t)b * 2048) * 2048 + h0;

  for (int c = 0; c < 4; ++c) {
    #pragma unroll
    for (int q = 0; q < 8; ++q) {
      int soff = q * 64 + srow;
      float v = x[xbase + (size_t)(c * 512 + soff) * 2048 + hh];
      lds[hh * 516 + (soff ^ ((soff >> 5) & 15))] = v;
    }
    __syncthreads();
    if ((lane >> 4) == c) {
      const int li = lane & 15;
      #pragma unroll
      for (int j = 0; j < 32; ++j) {
        ur[j] = lds[w * 516 + ((32 * li + j) ^ li)];
        ui[j] = 0.f;
      }
    }
    __syncthreads();
  }

  fwd_core(ur, ui, lane);
  {
    const int kap = bitrev6(lane);
    const unsigned int* grow = gt + (size_t)(h0 + w) * 2048;
    #pragma unroll
    for (int p = 0; p < 32; ++p) {
      unsigned int g = grow[(BR5[p] << 6) + kap];
      float gre = bflo(g), gim = bfhi(g);
      float t = ur[p] * gre - ui[p] * gim;
      ui[p] = ur[p] * gim + ui[p] * gre;
      ur[p] = t;
    }
  }
  inv_core(ur, ui, lane);

  for (int c = 0; c < 4; ++c) {
    if ((lane >> 4) == c) {
      const int li = lane & 15;
      #pragma unroll
      for (int r = 0; r < 32; ++r)
        lds[w * 516 + ((32 * li + r) ^ li)] = ur[r];
    }
    __syncthreads();
    #pragma unroll
    for (int q = 0; q < 8; ++q) {
      int soff = q * 64 + srow;
      float v = lds[hh * 516 + (soff ^ ((soff >> 5) & 15))];
      y[xbase + (size_t)(c * 512 + soff) * 2048 + hh] = f2bf(v);
    }
    __syncthreads();
  }
}

// ---------- GEMM fallback: m97-style 128x128 tile (R9 version) ----------
__global__ __launch_bounds__(256) void gemm_k(const unsigned short* __restrict__ A,
                                              const unsigned short* __restrict__ Bw,
                                              const float* __restrict__ bias,
                                              float* __restrict__ C) {
  __shared__ unsigned short sA[128 * 32];
  __shared__ unsigned short sB[128 * 32];
  const int tid = threadIdx.x;
  const int nwg = gridDim.x;
  const int cpx = nwg >> 3;
  const int bid = blockIdx.x;
  const int swz = (bid & 7) * cpx + (bid >> 3);
  const int bm = swz >> 4, bn = swz & 15;
  const int m0 = bm << 7, n0 = bn << 7;
  const int w = tid >> 6, lane = tid & 63;
  const int arow = tid >> 2, koff = (tid & 3) << 3;
  const unsigned short* gA = A + (size_t)(m0 + arow) * 2048 + koff;
  const unsigned short* gB = Bw + (size_t)(n0 + arow) * 2048 + koff;
  char* sAb = (char*)sA + w * 1024;
  char* sBb = (char*)sB + w * 1024;

  f32x4 acc[4][4];
  #pragma unroll
  for (int i = 0; i < 4; ++i)
    #pragma unroll
    for (int j = 0; j < 4; ++j) acc[i][j] = (f32x4){0.f, 0.f, 0.f, 0.f};

  const int wr = w >> 1, wc = w & 1;
  const int row16 = lane & 15, kb = lane >> 4;

  for (int k0 = 0; k0 < 2048; k0 += 32) {
    glds16(gA + k0, sAb);
    glds16(gA + 64 * 2048 + k0, sAb + 4096);
    glds16(gB + k0, sBb);
    glds16(gB + 64 * 2048 + k0, sBb + 4096);
    __syncthreads();
    bf16x8 af[4], bfr[4];
    #pragma unroll
    for (int i = 0; i < 4; ++i) {
      int r = (wr << 6) + (i << 4) + row16;
      af[i] = *(const bf16x8*)(sA + r * 32 + (kb << 3));
    }
    #pragma unroll
    for (int j2 = 0; j2 < 4; ++j2) {
      int r = (wc << 6) + (j2 << 4) + row16;
      bfr[j2] = *(const bf16x8*)(sB + r * 32 + (kb << 3));
    }
    #pragma unroll
    for (int i = 0; i < 4; ++i)
      #pragma unroll
      for (int j2 = 0; j2 < 4; ++j2)
        acc[i][j2] = __builtin_amdgcn_mfma_f32_16x16x32_bf16(af[i], bfr[j2], acc[i][j2], 0, 0, 0);
    __syncthreads();
  }

  const int rq = lane >> 4;
  #pragma unroll
  for (int j2 = 0; j2 < 4; ++j2) {
    int oc = n0 + (wc << 6) + (j2 << 4) + row16;
    float bj = bias[oc];
    #pragma unroll
    for (int i = 0; i < 4; ++i) {
      int mr = m0 + (wr << 6) + (i << 4) + (rq << 2);
      #pragma unroll
      for (int q = 0; q < 4; ++q)
        C[(size_t)(mr + q) * 2048 + oc] = acc[i][j2][q] + bj;
    }
  }
}

// ---------- GEMM main: 256x256 tile, 8 waves, 4-stage pipeline, counted vmcnt ----------
// (R10-verified: passed refcheck, beat 128^2 kernel by ~40 µs.)
__global__ __launch_bounds__(512) void gemm8_k(const unsigned short* __restrict__ A,
                                               const unsigned short* __restrict__ Bw,
                                               const float* __restrict__ bias,
                                               float* __restrict__ C) {
  extern __shared__ char lds[];   // 4 x (A 16KB + B 16KB) = 128 KiB
  const int tid = threadIdx.x;
  const int w = tid >> 6, lane = tid & 63;
  const int bid = blockIdx.x;
  const int swz = (bid & 7) * 64 + (bid >> 3);   // 512 wgs, 8 XCDs, bijective
  const int m0 = (swz >> 3) << 8;                // 64 row-tiles
  const int n0 = (swz & 7) << 8;                 // 8 col-tiles
  const int wr = w >> 2, wc = w & 3;             // 2M x 4N waves
  const int row16 = lane & 15, kb = lane >> 4;

  const int lr = lane >> 2, ls = lane & 3;
  const int r0 = (w << 5) + lr, r1 = r0 + 16;
  const unsigned short* pA0 = A  + (size_t)(m0 + r0) * 2048 + ((ls ^ ((r0 >> 1) & 3)) << 3);
  const unsigned short* pA1 = A  + (size_t)(m0 + r1) * 2048 + ((ls ^ ((r1 >> 1) & 3)) << 3);
  const unsigned short* pB0 = Bw + (size_t)(n0 + r0) * 2048 + ((ls ^ ((r0 >> 1) & 3)) << 3);
  const unsigned short* pB1 = Bw + (size_t)(n0 + r1) * 2048 + ((ls ^ ((r1 >> 1) & 3)) << 3);
  const int dW = w << 11;                        // wave's 32-row slice byte offset

  f32x4 acc[8][4];
  #pragma unroll
  for (int i = 0; i < 8; ++i)
    #pragma unroll
    for (int j = 0; j < 4; ++j) acc[i][j] = (f32x4){0.f, 0.f, 0.f, 0.f};

  auto STAGE = [&](int t) {
    char* base = lds + ((t & 3) << 15);
    const int k0 = t << 5;
    glds16(pA0 + k0, base + dW);
    glds16(pA1 + k0, base + dW + 1024);
    glds16(pB0 + k0, base + 16384 + dW);
    glds16(pB1 + k0, base + 16384 + dW + 1024);
  };
  auto COMPUTE = [&](int t) {
    const char* base = lds + ((t & 3) << 15);
    bf16x8 af[8], bfr[4];
    #pragma unroll
    for (int i = 0; i < 8; ++i) {
      const int r = (wr << 7) + (i << 4) + row16;
      af[i] = *(const bf16x8*)(base + (r << 6) + ((kb ^ ((r >> 1) & 3)) << 4));
    }
    #pragma unroll
    for (int j = 0; j < 4; ++j) {
      const int r = (wc << 6) + (j << 4) + row16;
      bfr[j] = *(const bf16x8*)(base + 16384 + (r << 6) + ((kb ^ ((r >> 1) & 3)) << 4));
    }
    #pragma unroll
    for (int i = 0; i < 8; ++i)
      #pragma unroll
      for (int j = 0; j < 4; ++j)
        acc[i][j] = __builtin_amdgcn_mfma_f32_16x16x32_bf16(af[i], bfr[j], acc[i][j], 0, 0, 0);
  };

  STAGE(0); STAGE(1); STAGE(2);
  asm volatile("s_waitcnt vmcnt(8)" ::: "memory");
  __builtin_amdgcn_s_barrier();
  __builtin_amdgcn_sched_barrier(0);

  for (int t = 0; t < 61; ++t) {
    STAGE(t + 3);
    COMPUTE(t);
    asm volatile("s_waitcnt vmcnt(8)" ::: "memory");
    __builtin_amdgcn_s_barrier();
    __builtin_amdgcn_sched_barrier(0);
  }
  COMPUTE(61);
  asm volatile("s_waitcnt vmcnt(4)" ::: "memory");
  __builtin_amdgcn_s_barrier();
  __builtin_amdgcn_sched_barrier(0);
  COMPUTE(62);
  asm volatile("s_waitcnt vmcnt(0)" ::: "memory");
  __builtin_amdgcn_s_barrier();
  __builtin_amdgcn_sched_barrier(0);
  COMPUTE(63);

  const int rq = lane >> 4;
  #pragma unroll
  for (int j = 0; j < 4; ++j) {
    const int oc = n0 + (wc << 6) + (j << 4) + row16;
    const float bj = bias[oc];
    #pragma unroll
    for (int i = 0; i < 8; ++i) {
      const int mr = m0 + (wr << 7) + (i << 4) + (rq << 2);
      #pragma unroll
      for (int q = 0; q < 4; ++q)
        C[(size_t)(mr + q) * 2048 + oc] = acc[i][j][q] + bj;
    }
  }
}

extern "C" void kernel_launch(void* const* d_in, const int* in_sizes, int n_in,
                              void* d_out, int out_size, void* d_ws, size_t ws_size,
                              hipStream_t stream) {
  const float* x  = (const float*)d_in[0];
  const float* gr = (const float*)d_in[1];
  const float* gi = (const float*)d_in[2];
  const float* W  = (const float*)d_in[3];
  const float* bs = (const float*)d_in[4];
  float* out = (float*)d_out;

  char* ws = (char*)d_ws;
  unsigned short* yb = (unsigned short*)ws;                          // 64 MB  y bf16 [b,s,h]
  unsigned short* Wb = (unsigned short*)(ws + (64ull << 20));        // 8 MB   W bf16
  unsigned int*   gt = (unsigned int*)(ws + (72ull << 20));          // 16 MB  gate (fallback)
  uint2*          pq = (uint2*)(ws + (72ull << 20));                 // 16 MB  pair gate (fast)
  float*          xT = (float*)(ws + (88ull << 20));                 // 128 MB x transposed [b,h,s]
  unsigned short* yT = (unsigned short*)(ws + (216ull << 20));       // 64 MB  y transposed [b,h,s]
  const bool fast = ws_size >= (280ull << 20);

  hipLaunchKernelGGL(wconv_k, dim3(4096), dim3(256), 0, stream, W, Wb);
  if (fast) {
    hipLaunchKernelGGL(gate_pair_k, dim3(64, 32), dim3(256), 0, stream, gr, gi, pq);
    hipLaunchKernelGGL(xtrans_k, dim3(64, 64, 8), dim3(256), 0, stream, x, xT);
    hipLaunchKernelGGL(fftp_k, dim3(2048), dim3(256), 0, stream, xT, pq, yT);
    hipLaunchKernelGGL(ytrans_k, dim3(32, 32, 8), dim3(256), 0, stream, yT, yb);
  } else {
    hipLaunchKernelGGL(gate_pack_k, dim3(64, 64), dim3(256), 0, stream, gr, gi, gt);
    hipLaunchKernelGGL(fft_gate_k, dim3(2048), dim3(512), 0, stream, x, gt, yb);
  }

  const bool big = hipFuncSetAttribute((const void*)gemm8_k,
                                       hipFuncAttributeMaxDynamicSharedMemorySize,
                                       131072) == hipSuccess;
  if (big) {
    hipLaunchKernelGGL(gemm8_k, dim3(512), dim3(512), 131072, stream, yb, Wb, bs, out);
  } else {
    hipLaunchKernelGGL(gemm_k, dim3(2048), dim3(256), 0, stream, yb, Wb, bs, out);
  }
}

// Round 13
// 373.929 us; speedup vs baseline: 1.4372x; 1.4372x over previous
//
#include <hip/hip_runtime.h>
#include <math.h>

typedef __attribute__((ext_vector_type(8))) short bf16x8;
typedef __attribute__((ext_vector_type(4))) float f32x4;

__device__ __forceinline__ unsigned short f2bf(float f) {
  unsigned int u = __float_as_uint(f);
  unsigned int r = (u + 0x7fffu + ((u >> 16) & 1u)) >> 16;
  return (unsigned short)r;
}
__device__ __forceinline__ unsigned int pack2bf(float a, float b) {
  return (unsigned int)f2bf(a) | ((unsigned int)f2bf(b) << 16);
}
__device__ __forceinline__ float bflo(unsigned int g) { return __uint_as_float(g << 16); }
__device__ __forceinline__ float bfhi(unsigned int g) { return __uint_as_float(g & 0xffff0000u); }

__device__ __forceinline__ void glds16(const void* gp, void* lp) {
  __builtin_amdgcn_global_load_lds(
      (const __attribute__((address_space(1))) void*)gp,
      (__attribute__((address_space(3))) void*)lp, 16, 0, 0);
}

// cos/sin(pi*j/16), j=0..15 — cover all in-lane FFT16/FFT32 twiddles
__device__ __constant__ float CW16[16] = {
  1.0f, 0.9807852804032304f, 0.9238795325112867f, 0.8314696123025452f,
  0.7071067811865476f, 0.5555702330196022f, 0.3826834323650898f, 0.19509032201612828f,
  0.0f, -0.19509032201612828f, -0.3826834323650898f, -0.5555702330196022f,
  -0.7071067811865476f, -0.8314696123025452f, -0.9238795325112867f, -0.9807852804032304f};
__device__ __constant__ float SW16[16] = {
  0.0f, 0.19509032201612828f, 0.3826834323650898f, 0.5555702330196022f,
  0.7071067811865476f, 0.8314696123025452f, 0.9238795325112867f, 0.9807852804032304f,
  1.0f, 0.9807852804032304f, 0.9238795325112867f, 0.8314696123025452f,
  0.7071067811865476f, 0.5555702330196022f, 0.3826834323650898f, 0.19509032201612828f};
__device__ __constant__ int BR5[32] = {
  0,16,8,24,4,20,12,28,2,18,10,26,6,22,14,30,
  1,17,9,25,5,21,13,29,3,19,11,27,7,23,15,31};

__device__ __forceinline__ int bitrev6(int l) {
  return ((l&1)<<5)|((l&2)<<3)|((l&4)<<1)|((l&8)>>1)|((l&16)>>3)|((l&32)>>5);
}

// hardware sin/cos: input in REVOLUTIONS (angle/2pi); all our args are in [0,1)
__device__ __forceinline__ float hsin(float rev) { return __builtin_amdgcn_sinf(rev); }
__device__ __forceinline__ float hcos(float rev) { return __builtin_amdgcn_cosf(rev); }

// ================= 2048-point cores (fallback path only; R10 form, no fences) =================
__device__ __forceinline__ void fwd_core(float (&ur)[32], float (&ui)[32], const int lane) {
  #pragma unroll
  for (int s = 0; s < 6; ++s) {
    const int h = 32 >> s;
    const int j = lane & (h - 1);
    const float rev = (float)j * (0.5f / (float)h);
    const bool hi = (lane & h) != 0;
    const float c  = hi ? hcos(rev) : 1.0f;
    const float sv = hi ? hsin(rev) : 0.0f;
    const float sgn = hi ? -1.0f : 1.0f;
    #pragma unroll
    for (int r = 0; r < 32; ++r) {
      float pr = __shfl_xor(ur[r], h, 64);
      float pi = __shfl_xor(ui[r], h, 64);
      float tr = fmaf(sgn, ur[r], pr);
      float ti = fmaf(sgn, ui[r], pi);
      ur[r] = fmaf(ti, sv, tr * c);
      ui[r] = fmaf(-tr, sv, ti * c);
    }
  }
  const int kap = bitrev6(lane);
  #pragma unroll
  for (int j = 1; j < 32; ++j) {
    const float rev = (float)(j * kap) * (1.0f / 2048.0f);
    const float sn = hsin(rev), cs = hcos(rev);
    float t = ur[j] * cs + ui[j] * sn;
    ui[j] = ui[j] * cs - ur[j] * sn;
    ur[j] = t;
  }
  #pragma unroll
  for (int s = 0; s < 5; ++s) {
    const int h = 16 >> s;
    #pragma unroll
    for (int i = 0; i < 32; ++i) if (!(i & h)) {
      const int tw = (i & (h - 1)) * (16 / h);
      float dr = ur[i] - ur[i + h], di = ui[i] - ui[i + h];
      ur[i] += ur[i + h]; ui[i] += ui[i + h];
      ur[i + h] = dr * CW16[tw] + di * SW16[tw];
      ui[i + h] = di * CW16[tw] - dr * SW16[tw];
    }
  }
}

__device__ __forceinline__ void inv_core(float (&ur)[32], float (&ui)[32], const int lane) {
  const int kap = bitrev6(lane);
  #pragma unroll
  for (int s = 0; s < 5; ++s) {
    const int h = 1 << s;
    #pragma unroll
    for (int i = 0; i < 32; ++i) if (!(i & h)) {
      const int tw = (i & (h - 1)) * (16 / h);
      float tr2 = ur[i + h] * CW16[tw] - ui[i + h] * SW16[tw];
      float ti2 = ui[i + h] * CW16[tw] + ur[i + h] * SW16[tw];
      ur[i + h] = ur[i] - tr2; ui[i + h] = ui[i] - ti2;
      ur[i] += tr2; ui[i] += ti2;
    }
  }
  #pragma unroll
  for (int j = 1; j < 32; ++j) {
    const float rev = (float)(j * kap) * (1.0f / 2048.0f);
    const float sn = hsin(rev), cs = hcos(rev);
    float t = ur[j] * cs - ui[j] * sn;
    ui[j] = ui[j] * cs + ur[j] * sn;
    ur[j] = t;
  }
  #pragma unroll
  for (int s = 0; s < 6; ++s) {
    const int h = 1 << s;
    const int j = lane & (h - 1);
    const float rev = (float)j * (0.5f / (float)h);
    const bool hi = (lane & h) != 0;
    const float c  = hi ? hcos(rev) : 1.0f;
    const float sv = hi ? hsin(rev) : 0.0f;
    const float sgn = hi ? -1.0f : 1.0f;
    #pragma unroll
    for (int r = 0; r < 32; ++r) {
      float vr = fmaf(-ui[r], sv, ur[r] * c);
      float vi = fmaf(ur[r], sv, ui[r] * c);
      float pvr = __shfl_xor(vr, h, 64);
      float pvi = __shfl_xor(vi, h, 64);
      ur[r] = fmaf(sgn, vr, pvr);
      ui[r] = fmaf(sgn, vi, pvi);
    }
  }
}

// ---------- gate transpose + Hermitian extend + pack (fallback path) ----------
__global__ __launch_bounds__(256) void gate_pack_k(const float* __restrict__ gr,
                                                   const float* __restrict__ gi,
                                                   unsigned int* __restrict__ gt) {
  __shared__ float tr[32][33];
  __shared__ float ti[32][33];
  const int t = threadIdx.x;
  const int k0 = blockIdx.x * 32, hb = blockIdx.y * 32;
  const int hx = t & 31, fr = t >> 5;
  #pragma unroll
  for (int p = 0; p < 4; ++p) {
    int ff = p * 8 + fr;
    int k = k0 + ff;
    int f = (k <= 1024) ? k : (2048 - k);
    float sg = (k <= 1024) ? 1.f : -1.f;
    tr[ff][hx] = gr[(size_t)f * 2048 + hb + hx] * (1.f / 2048.f);
    ti[ff][hx] = sg * gi[(size_t)f * 2048 + hb + hx] * (1.f / 2048.f);
  }
  __syncthreads();
  const int kk = t & 31, hr = t >> 5;
  #pragma unroll
  for (int p = 0; p < 4; ++p) {
    int hl = p * 8 + hr;
    float re = tr[kk][hl], im = ti[kk][hl];
    gt[(size_t)(hb + hl) * 2048 + k0 + kk] =
        (unsigned int)f2bf(re) | ((unsigned int)f2bf(im) << 16);
  }
}

// ---------- A/B table for the rfft path ----------
// Z'[k] = A[h,k] Z[k] + B[h,k] conj(Z[1024-k]), theta = pi*k/1024:
//   Sg=(G[k]+conj(G[1024-k]))/2, Dg=(G[k]-conj(G[1024-k]))/2
//   A = (Sg - sin(theta) Dg)/1024,  B = i cos(theta) Dg / 1024
// k=0 (numpy irfft semantics: imag of bins 0,1024 ignored):
//   A = (Re G[0]+Re G[1024])/2/1024,  B = i (Re G[0]-Re G[1024])/2/1024
// Layout ab[h][k] as (packA, packB); verified: G==1 -> A=1/1024, B=0 (identity).
__global__ __launch_bounds__(256) void gate_ab_k(const float* __restrict__ gr,
                                                 const float* __restrict__ gi,
                                                 uint2* __restrict__ ab) {
  __shared__ unsigned int uA[32][33];
  __shared__ unsigned int uB[32][33];
  const int t = threadIdx.x;
  const int k0 = blockIdx.x * 32, h0 = blockIdx.y * 32;
  const int c = t & 31, r = t >> 5;
  #pragma unroll
  for (int pp = 0; pp < 4; ++pp) {
    const int kk = pp * 8 + r;
    const int k = k0 + kk;
    const int h = h0 + c;
    const float gkr = gr[(size_t)k * 2048 + h];
    const float gki = gi[(size_t)k * 2048 + h];
    const float gcr = gr[(size_t)(1024 - k) * 2048 + h];
    const float gci = gi[(size_t)(1024 - k) * 2048 + h];
    const float inv = 1.0f / 1024.0f;
    float Ar, Ai, Br, Bi;
    if (k == 0) {
      Ar = (gkr + gcr) * 0.5f * inv; Ai = 0.f;
      Br = 0.f; Bi = (gkr - gcr) * 0.5f * inv;
    } else {
      const float rev = (float)k * (1.0f / 2048.0f);   // theta = pi*k/1024
      const float sn = hsin(rev), cs = hcos(rev);
      const float Sr = (gkr + gcr) * 0.5f, Si = (gki - gci) * 0.5f;
      const float Dr = (gkr - gcr) * 0.5f, Di = (gki + gci) * 0.5f;
      Ar = (Sr - sn * Dr) * inv; Ai = (Si - sn * Di) * inv;
      Br = (-cs * Di) * inv;     Bi = (cs * Dr) * inv;
    }
    uA[kk][c] = pack2bf(Ar, Ai);
    uB[kk][c] = pack2bf(Br, Bi);
  }
  __syncthreads();
  #pragma unroll
  for (int pp = 0; pp < 4; ++pp) {
    const int hh = pp * 8 + r;
    ab[(size_t)(h0 + hh) * 1024 + k0 + c] = make_uint2(uA[c][hh], uB[c][hh]);
  }
}

// ---------- W f32 -> bf16 ----------
__global__ __launch_bounds__(256) void wconv_k(const float* __restrict__ W,
                                               unsigned short* __restrict__ Wb) {
  int i = blockIdx.x * 256 + threadIdx.x;
  float4 v = ((const float4*)W)[i];
  ushort4 o;
  o.x = f2bf(v.x); o.y = f2bf(v.y); o.z = f2bf(v.z); o.w = f2bf(v.w);
  ((ushort4*)Wb)[i] = o;
}

// ---------- T1: x [b,s,h] -> xT [b,h,s], f32 32x32 tiles ----------
__global__ __launch_bounds__(256) void xtrans_k(const float* __restrict__ x,
                                                float* __restrict__ xT) {
  __shared__ float t[32][33];
  const int b = blockIdx.z;
  const int s0 = blockIdx.x * 32, h0 = blockIdx.y * 32;
  const float* xb = x + ((size_t)b * 2048) * 2048;
  float* xTb = xT + ((size_t)b * 2048) * 2048;
  const int c = threadIdx.x & 31, r = threadIdx.x >> 5;
  #pragma unroll
  for (int p = 0; p < 4; ++p) {
    int rr = p * 8 + r;
    t[rr][c] = xb[(size_t)(s0 + rr) * 2048 + h0 + c];
  }
  __syncthreads();
  #pragma unroll
  for (int p = 0; p < 4; ++p) {
    int rr = p * 8 + r;
    xTb[(size_t)(h0 + rr) * 2048 + s0 + c] = t[c][rr];
  }
}

// ---------- T2: yT [b,h,s] -> y [b,s,h], bf16 64x64 tiles ----------
__global__ __launch_bounds__(256) void ytrans_k(const unsigned short* __restrict__ yT,
                                                unsigned short* __restrict__ y) {
  __shared__ unsigned short t[64][66];
  const int b = blockIdx.z;
  const int h0 = blockIdx.x * 64, s0 = blockIdx.y * 64;
  const unsigned short* src = yT + ((size_t)b * 2048 + h0) * 2048 + s0;
  unsigned short* dst = y + ((size_t)b * 2048 + s0) * 2048 + h0;
  const int c = threadIdx.x & 15, r = threadIdx.x >> 4;
  #pragma unroll
  for (int p = 0; p < 4; ++p) {
    int rr = p * 16 + r;
    ushort4 v = *(const ushort4*)(src + (size_t)rr * 2048 + c * 4);
    *(ushort4*)&t[rr][c * 4] = v;
  }
  __syncthreads();
  #pragma unroll
  for (int p = 0; p < 4; ++p) {
    int rr = p * 16 + r;
    ushort4 o;
    o.x = t[c * 4 + 0][rr]; o.y = t[c * 4 + 1][rr];
    o.z = t[c * 4 + 2][rr]; o.w = t[c * 4 + 3][rr];
    *(ushort4*)(dst + (size_t)rr * 2048 + c * 4) = o;
  }
}

// ---------- rfft FFT: one wave per column; z[n]=x[2n]+i*x[2n+1], FFT-1024 ----------
// State: ur[16]+ui[16] = 32 regs (half of the 2048-pair version) -> fits the
// proven 128-VGPR regime with headroom; R5-R11 showed the 64-reg state can
// never avoid either spill (128 cap) or occupancy loss (220 free).
// Layout: n = j + 16*lane; cross-lane DIF-64 over lane, mid-twiddle
// e^{-2pi i j kap/1024}, in-lane DIF-16 -> reg p holds k = kap + 64*bitrev4(p).
// Partner of k (=1024-k) at lane bitrev6(64-kap), reg 15-p; lane 0 self-closed
// via P0L16 snapshot (exact analog of the HW-verified 2048 pair kernel).
__global__ __attribute__((amdgpu_flat_work_group_size(256, 256)))
__attribute__((amdgpu_waves_per_eu(2, 4)))
void fftr_k(const float* __restrict__ xT,
            const uint2* __restrict__ ab,
            unsigned short* __restrict__ yT) {
  __shared__ float snap[4][32];
  const int tid = threadIdx.x;
  const int w = tid >> 6, lane = tid & 63;
  const size_t col = (size_t)blockIdx.x * 4 + w;   // b*2048 + h
  const int h = (int)(col & 2047);

  float ur[16], ui[16];
  const float4* xc = (const float4*)(xT + col * 2048);
  #pragma unroll
  for (int q = 0; q < 8; ++q) {
    float4 v = xc[lane * 8 + q];
    ur[2 * q]     = v.x; ui[2 * q]     = v.y;   // z[n]=x[2n]+i x[2n+1], n=16*lane+2q(+1)
    ur[2 * q + 1] = v.z; ui[2 * q + 1] = v.w;
  }

  // ---- forward cross-lane DIF-64 (branchless) ----
  #pragma unroll
  for (int s = 0; s < 6; ++s) {
    const int hh = 32 >> s;
    const int j = lane & (hh - 1);
    const float rev = (float)j * (0.5f / (float)hh);
    const bool hi = (lane & hh) != 0;
    const float c  = hi ? hcos(rev) : 1.0f;
    const float sv = hi ? hsin(rev) : 0.0f;
    const float sgn = hi ? -1.0f : 1.0f;
    #pragma unroll
    for (int r = 0; r < 16; ++r) {
      float pr = __shfl_xor(ur[r], hh, 64);
      float pi = __shfl_xor(ui[r], hh, 64);
      float tr = fmaf(sgn, ur[r], pr);
      float ti = fmaf(sgn, ui[r], pi);
      ur[r] = fmaf(ti, sv, tr * c);
      ui[r] = fmaf(-tr, sv, ti * c);
    }
  }
  const int kap = bitrev6(lane);
  // ---- forward mid-twiddle e^{-2pi i j kap/1024} ----
  #pragma unroll
  for (int j = 1; j < 16; ++j) {
    const float rev = (float)(j * kap) * (1.0f / 1024.0f);  // <= 0.923
    const float sn = hsin(rev), cs = hcos(rev);
    float t = ur[j] * cs + ui[j] * sn;
    ui[j] = ui[j] * cs - ur[j] * sn;
    ur[j] = t;
  }
  // ---- in-lane DIF-16 ----
  #pragma unroll
  for (int s = 0; s < 4; ++s) {
    const int hh = 8 >> s;
    #pragma unroll
    for (int i = 0; i < 16; ++i) if (!(i & hh)) {
      const int tw = (i & (hh - 1)) * (16 / hh);
      float dr = ur[i] - ur[i + hh], di = ui[i] - ui[i + hh];
      ur[i] += ur[i + hh]; ui[i] += ui[i + hh];
      ur[i + hh] = dr * CW16[tw] + di * SW16[tw];
      ui[i + hh] = di * CW16[tw] - dr * SW16[tw];
    }
  }

  // ---- gate: Z'[k] = A Z[k] + B conj(Z[1024-k]) ----
  if (lane == 0) {
    #pragma unroll
    for (int p = 0; p < 16; ++p) { snap[w][2 * p] = ur[p]; snap[w][2 * p + 1] = ui[p]; }
  }
  const int lsrc = bitrev6((64 - kap) & 63);
  const uint2* abrow = ab + (size_t)h * 1024;
  constexpr int BR4[16]   = {0,8,4,12,2,10,6,14,1,9,5,13,3,11,7,15};
  constexpr int P0L16[16] = {0,1,3,2,7,6,5,4,15,14,13,12,11,10,9,8};
  const bool l0 = (lane == 0);
  #pragma unroll
  for (int p = 0; p < 8; ++p) {
    const int pb = 15 - p;
    float arp = __shfl(ur[pb], lsrc), aip = __shfl(ui[pb], lsrc);  // partner of reg p
    float arq = __shfl(ur[p], lsrc),  aiq = __shfl(ui[p], lsrc);   // partner of reg pb
    float s0r = snap[w][2 * P0L16[p]],  s0i = snap[w][2 * P0L16[p] + 1];
    float s1r = snap[w][2 * P0L16[pb]], s1i = snap[w][2 * P0L16[pb] + 1];
    arp = l0 ? s0r : arp;  aip = l0 ? s0i : aip;
    arq = l0 ? s1r : arq;  aiq = l0 ? s1i : aiq;
    uint2 gp = abrow[(BR4[p]  << 6) + kap];
    uint2 gq = abrow[(BR4[pb] << 6) + kap];
    {
      float Ar = bflo(gp.x), Ai = bfhi(gp.x), Br = bflo(gp.y), Bi = bfhi(gp.y);
      float zr = ur[p], zi = ui[p];
      ur[p] = Ar * zr - Ai * zi + Br * arp + Bi * aip;
      ui[p] = Ar * zi + Ai * zr + Bi * arp - Br * aip;
    }
    {
      float Ar = bflo(gq.x), Ai = bfhi(gq.x), Br = bflo(gq.y), Bi = bfhi(gq.y);
      float zr = ur[pb], zi = ui[pb];
      ur[pb] = Ar * zr - Ai * zi + Br * arq + Bi * aiq;
      ui[pb] = Ar * zi + Ai * zr + Bi * arq - Br * aiq;
    }
  }

  // ---- inverse: in-lane DIT-16, inv mid-twiddle, cross-lane DIT-64 ----
  #pragma unroll
  for (int s = 0; s < 4; ++s) {
    const int hh = 1 << s;
    #pragma unroll
    for (int i = 0; i < 16; ++i) if (!(i & hh)) {
      const int tw = (i & (hh - 1)) * (16 / hh);
      float tr2 = ur[i + hh] * CW16[tw] - ui[i + hh] * SW16[tw];
      float ti2 = ui[i + hh] * CW16[tw] + ur[i + hh] * SW16[tw];
      ur[i + hh] = ur[i] - tr2; ui[i + hh] = ui[i] - ti2;
      ur[i] += tr2; ui[i] += ti2;
    }
  }
  #pragma unroll
  for (int j = 1; j < 16; ++j) {
    const float rev = (float)(j * kap) * (1.0f / 1024.0f);
    const float sn = hsin(rev), cs = hcos(rev);
    float t = ur[j] * cs - ui[j] * sn;
    ui[j] = ui[j] * cs + ur[j] * sn;
    ur[j] = t;
  }
  #pragma unroll
  for (int s = 0; s < 6; ++s) {
    const int hh = 1 << s;
    const int j = lane & (hh - 1);
    const float rev = (float)j * (0.5f / (float)hh);
    const bool hi = (lane & hh) != 0;
    const float c  = hi ? hcos(rev) : 1.0f;
    const float sv = hi ? hsin(rev) : 0.0f;
    const float sgn = hi ? -1.0f : 1.0f;
    #pragma unroll
    for (int r = 0; r < 16; ++r) {
      float vr = fmaf(-ui[r], sv, ur[r] * c);
      float vi = fmaf(ur[r], sv, ui[r] * c);
      float pvr = __shfl_xor(vr, hh, 64);
      float pvi = __shfl_xor(vi, hh, 64);
      ur[r] = fmaf(sgn, vr, pvr);
      ui[r] = fmaf(sgn, vi, pvi);
    }
  }

  // ---- store: u32 j = (y[32*lane+2j], y[32*lane+2j+1]); 64B contiguous/lane ----
  uint4* dst = (uint4*)(yT + col * 2048) + lane * 4;
  #pragma unroll
  for (int g = 0; g < 4; ++g) {
    uint4 o;
    o.x = pack2bf(ur[4 * g + 0], ui[4 * g + 0]);
    o.y = pack2bf(ur[4 * g + 1], ui[4 * g + 1]);
    o.z = pack2bf(ur[4 * g + 2], ui[4 * g + 2]);
    o.w = pack2bf(ur[4 * g + 3], ui[4 * g + 3]);
    dst[g] = o;
  }
}

// ---------- fallback (R3-proven): FFT-2048 reading x directly via LDS staging ----------
__global__ __attribute__((amdgpu_flat_work_group_size(512, 512)))
__attribute__((amdgpu_waves_per_eu(2, 4)))
void fft_gate_k(const float* __restrict__ x,
                const unsigned int* __restrict__ gt,
                unsigned short* __restrict__ y) {
  __shared__ float lds[8 * 516];
  const int tid = threadIdx.x;
  const int w = tid >> 6;
  const int lane = tid & 63;
  const int bid = blockIdx.x;
  const int swz = (bid & 7) * 256 + (bid >> 3);
  const int h0 = (swz & 255) << 3;
  const int b = swz >> 8;
  const int hh = tid & 7, srow = tid >> 3;

  float ur[32], ui[32];
  const size_t xbase = ((size_t)b * 2048) * 2048 + h0;

  for (int c = 0; c < 4; ++c) {
    #pragma unroll
    for (int q = 0; q < 8; ++q) {
      int soff = q * 64 + srow;
      float v = x[xbase + (size_t)(c * 512 + soff) * 2048 + hh];
      lds[hh * 516 + (soff ^ ((soff >> 5) & 15))] = v;
    }
    __syncthreads();
    if ((lane >> 4) == c) {
      const int li = lane & 15;
      #pragma unroll
      for (int j = 0; j < 32; ++j) {
        ur[j] = lds[w * 516 + ((32 * li + j) ^ li)];
        ui[j] = 0.f;
      }
    }
    __syncthreads();
  }

  fwd_core(ur, ui, lane);
  {
    const int kap = bitrev6(lane);
    const unsigned int* grow = gt + (size_t)(h0 + w) * 2048;
    #pragma unroll
    for (int p = 0; p < 32; ++p) {
      unsigned int g = grow[(BR5[p] << 6) + kap];
      float gre = bflo(g), gim = bfhi(g);
      float t = ur[p] * gre - ui[p] * gim;
      ui[p] = ur[p] * gim + ui[p] * gre;
      ur[p] = t;
    }
  }
  inv_core(ur, ui, lane);

  for (int c = 0; c < 4; ++c) {
    if ((lane >> 4) == c) {
      const int li = lane & 15;
      #pragma unroll
      for (int r = 0; r < 32; ++r)
        lds[w * 516 + ((32 * li + r) ^ li)] = ur[r];
    }
    __syncthreads();
    #pragma unroll
    for (int q = 0; q < 8; ++q) {
      int soff = q * 64 + srow;
      float v = lds[hh * 516 + (soff ^ ((soff >> 5) & 15))];
      y[xbase + (size_t)(c * 512 + soff) * 2048 + hh] = f2bf(v);
    }
    __syncthreads();
  }
}

// ---------- GEMM fallback: m97-style 128x128 tile ----------
__global__ __launch_bounds__(256) void gemm_k(const unsigned short* __restrict__ A,
                                              const unsigned short* __restrict__ Bw,
                                              const float* __restrict__ bias,
                                              float* __restrict__ C) {
  __shared__ unsigned short sA[128 * 32];
  __shared__ unsigned short sB[128 * 32];
  const int tid = threadIdx.x;
  const int nwg = gridDim.x;
  const int cpx = nwg >> 3;
  const int bid = blockIdx.x;
  const int swz = (bid & 7) * cpx + (bid >> 3);
  const int bm = swz >> 4, bn = swz & 15;
  const int m0 = bm << 7, n0 = bn << 7;
  const int w = tid >> 6, lane = tid & 63;
  const int arow = tid >> 2, koff = (tid & 3) << 3;
  const unsigned short* gA = A + (size_t)(m0 + arow) * 2048 + koff;
  const unsigned short* gB = Bw + (size_t)(n0 + arow) * 2048 + koff;
  char* sAb = (char*)sA + w * 1024;
  char* sBb = (char*)sB + w * 1024;

  f32x4 acc[4][4];
  #pragma unroll
  for (int i = 0; i < 4; ++i)
    #pragma unroll
    for (int j = 0; j < 4; ++j) acc[i][j] = (f32x4){0.f, 0.f, 0.f, 0.f};

  const int wr = w >> 1, wc = w & 1;
  const int row16 = lane & 15, kb = lane >> 4;

  for (int k0 = 0; k0 < 2048; k0 += 32) {
    glds16(gA + k0, sAb);
    glds16(gA + 64 * 2048 + k0, sAb + 4096);
    glds16(gB + k0, sBb);
    glds16(gB + 64 * 2048 + k0, sBb + 4096);
    __syncthreads();
    bf16x8 af[4], bfr[4];
    #pragma unroll
    for (int i = 0; i < 4; ++i) {
      int r = (wr << 6) + (i << 4) + row16;
      af[i] = *(const bf16x8*)(sA + r * 32 + (kb << 3));
    }
    #pragma unroll
    for (int j2 = 0; j2 < 4; ++j2) {
      int r = (wc << 6) + (j2 << 4) + row16;
      bfr[j2] = *(const bf16x8*)(sB + r * 32 + (kb << 3));
    }
    #pragma unroll
    for (int i = 0; i < 4; ++i)
      #pragma unroll
      for (int j2 = 0; j2 < 4; ++j2)
        acc[i][j2] = __builtin_amdgcn_mfma_f32_16x16x32_bf16(af[i], bfr[j2], acc[i][j2], 0, 0, 0);
    __syncthreads();
  }

  const int rq = lane >> 4;
  #pragma unroll
  for (int j2 = 0; j2 < 4; ++j2) {
    int oc = n0 + (wc << 6) + (j2 << 4) + row16;
    float bj = bias[oc];
    #pragma unroll
    for (int i = 0; i < 4; ++i) {
      int mr = m0 + (wr << 6) + (i << 4) + (rq << 2);
      #pragma unroll
      for (int q = 0; q < 4; ++q)
        C[(size_t)(mr + q) * 2048 + oc] = acc[i][j2][q] + bj;
    }
  }
}

// ---------- GEMM main: 256x256 tile, 8 waves, 4-stage pipeline (R10-verified) ----------
__global__ __launch_bounds__(512) void gemm8_k(const unsigned short* __restrict__ A,
                                               const unsigned short* __restrict__ Bw,
                                               const float* __restrict__ bias,
                                               float* __restrict__ C) {
  extern __shared__ char lds[];   // 4 x (A 16KB + B 16KB) = 128 KiB
  const int tid = threadIdx.x;
  const int w = tid >> 6, lane = tid & 63;
  const int bid = blockIdx.x;
  const int swz = (bid & 7) * 64 + (bid >> 3);
  const int m0 = (swz >> 3) << 8;
  const int n0 = (swz & 7) << 8;
  const int wr = w >> 2, wc = w & 3;
  const int row16 = lane & 15, kb = lane >> 4;

  const int lr = lane >> 2, ls = lane & 3;
  const int r0 = (w << 5) + lr, r1 = r0 + 16;
  const unsigned short* pA0 = A  + (size_t)(m0 + r0) * 2048 + ((ls ^ ((r0 >> 1) & 3)) << 3);
  const unsigned short* pA1 = A  + (size_t)(m0 + r1) * 2048 + ((ls ^ ((r1 >> 1) & 3)) << 3);
  const unsigned short* pB0 = Bw + (size_t)(n0 + r0) * 2048 + ((ls ^ ((r0 >> 1) & 3)) << 3);
  const unsigned short* pB1 = Bw + (size_t)(n0 + r1) * 2048 + ((ls ^ ((r1 >> 1) & 3)) << 3);
  const int dW = w << 11;

  f32x4 acc[8][4];
  #pragma unroll
  for (int i = 0; i < 8; ++i)
    #pragma unroll
    for (int j = 0; j < 4; ++j) acc[i][j] = (f32x4){0.f, 0.f, 0.f, 0.f};

  auto STAGE = [&](int t) {
    char* base = lds + ((t & 3) << 15);
    const int k0 = t << 5;
    glds16(pA0 + k0, base + dW);
    glds16(pA1 + k0, base + dW + 1024);
    glds16(pB0 + k0, base + 16384 + dW);
    glds16(pB1 + k0, base + 16384 + dW + 1024);
  };
  auto COMPUTE = [&](int t) {
    const char* base = lds + ((t & 3) << 15);
    bf16x8 af[8], bfr[4];
    #pragma unroll
    for (int i = 0; i < 8; ++i) {
      const int r = (wr << 7) + (i << 4) + row16;
      af[i] = *(const bf16x8*)(base + (r << 6) + ((kb ^ ((r >> 1) & 3)) << 4));
    }
    #pragma unroll
    for (int j = 0; j < 4; ++j) {
      const int r = (wc << 6) + (j << 4) + row16;
      bfr[j] = *(const bf16x8*)(base + 16384 + (r << 6) + ((kb ^ ((r >> 1) & 3)) << 4));
    }
    #pragma unroll
    for (int i = 0; i < 8; ++i)
      #pragma unroll
      for (int j = 0; j < 4; ++j)
        acc[i][j] = __builtin_amdgcn_mfma_f32_16x16x32_bf16(af[i], bfr[j], acc[i][j], 0, 0, 0);
  };

  STAGE(0); STAGE(1); STAGE(2);
  asm volatile("s_waitcnt vmcnt(8)" ::: "memory");
  __builtin_amdgcn_s_barrier();
  __builtin_amdgcn_sched_barrier(0);

  for (int t = 0; t < 61; ++t) {
    STAGE(t + 3);
    COMPUTE(t);
    asm volatile("s_waitcnt vmcnt(8)" ::: "memory");
    __builtin_amdgcn_s_barrier();
    __builtin_amdgcn_sched_barrier(0);
  }
  COMPUTE(61);
  asm volatile("s_waitcnt vmcnt(4)" ::: "memory");
  __builtin_amdgcn_s_barrier();
  __builtin_amdgcn_sched_barrier(0);
  COMPUTE(62);
  asm volatile("s_waitcnt vmcnt(0)" ::: "memory");
  __builtin_amdgcn_s_barrier();
  __builtin_amdgcn_sched_barrier(0);
  COMPUTE(63);

  const int rq = lane >> 4;
  #pragma unroll
  for (int j = 0; j < 4; ++j) {
    const int oc = n0 + (wc << 6) + (j << 4) + row16;
    const float bj = bias[oc];
    #pragma unroll
    for (int i = 0; i < 8; ++i) {
      const int mr = m0 + (wr << 7) + (i << 4) + (rq << 2);
      #pragma unroll
      for (int q = 0; q < 4; ++q)
        C[(size_t)(mr + q) * 2048 + oc] = acc[i][j][q] + bj;
    }
  }
}

extern "C" void kernel_launch(void* const* d_in, const int* in_sizes, int n_in,
                              void* d_out, int out_size, void* d_ws, size_t ws_size,
                              hipStream_t stream) {
  const float* x  = (const float*)d_in[0];
  const float* gr = (const float*)d_in[1];
  const float* gi = (const float*)d_in[2];
  const float* W  = (const float*)d_in[3];
  const float* bs = (const float*)d_in[4];
  float* out = (float*)d_out;

  char* ws = (char*)d_ws;
  unsigned short* yb = (unsigned short*)ws;                          // 64 MB  y bf16 [b,s,h]
  unsigned short* Wb = (unsigned short*)(ws + (64ull << 20));        // 8 MB   W bf16
  unsigned int*   gt = (unsigned int*)(ws + (72ull << 20));          // 16 MB  gate (fallback)
  uint2*          ab = (uint2*)(ws + (72ull << 20));                 // 16 MB  A/B table (fast)
  float*          xT = (float*)(ws + (88ull << 20));                 // 128 MB x transposed [b,h,s]
  unsigned short* yT = (unsigned short*)(ws + (216ull << 20));       // 64 MB  y transposed [b,h,s]
  const bool fast = ws_size >= (280ull << 20);

  hipLaunchKernelGGL(wconv_k, dim3(4096), dim3(256), 0, stream, W, Wb);
  if (fast) {
    hipLaunchKernelGGL(gate_ab_k, dim3(32, 64), dim3(256), 0, stream, gr, gi, ab);
    hipLaunchKernelGGL(xtrans_k, dim3(64, 64, 8), dim3(256), 0, stream, x, xT);
    hipLaunchKernelGGL(fftr_k, dim3(4096), dim3(256), 0, stream, xT, ab, yT);
    hipLaunchKernelGGL(ytrans_k, dim3(32, 32, 8), dim3(256), 0, stream, yT, yb);
  } else {
    hipLaunchKernelGGL(gate_pack_k, dim3(64, 64), dim3(256), 0, stream, gr, gi, gt);
    hipLaunchKernelGGL(fft_gate_k, dim3(2048), dim3(512), 0, stream, x, gt, yb);
  }

  const bool big = hipFuncSetAttribute((const void*)gemm8_k,
                                       hipFuncAttributeMaxDynamicSharedMemorySize,
                                       131072) == hipSuccess;
  if (big) {
    hipLaunchKernelGGL(gemm8_k, dim3(512), dim3(512), 131072, stream, yb, Wb, bs, out);
  } else {
    hipLaunchKernelGGL(gemm_k, dim3(2048), dim3(256), 0, stream, yb, Wb, bs, out);
  }
}

// Round 14
// 366.936 us; speedup vs baseline: 1.4646x; 1.0191x over previous
//
#include <hip/hip_runtime.h>
#include <math.h>

typedef __attribute__((ext_vector_type(8))) short bf16x8;
typedef __attribute__((ext_vector_type(4))) float f32x4;

__device__ __forceinline__ unsigned short f2bf(float f) {
  unsigned int u = __float_as_uint(f);
  unsigned int r = (u + 0x7fffu + ((u >> 16) & 1u)) >> 16;
  return (unsigned short)r;
}
__device__ __forceinline__ unsigned int pack2bf(float a, float b) {
  return (unsigned int)f2bf(a) | ((unsigned int)f2bf(b) << 16);
}
__device__ __forceinline__ float bflo(unsigned int g) { return __uint_as_float(g << 16); }
__device__ __forceinline__ float bfhi(unsigned int g) { return __uint_as_float(g & 0xffff0000u); }

__device__ __forceinline__ void glds16(const void* gp, void* lp) {
  __builtin_amdgcn_global_load_lds(
      (const __attribute__((address_space(1))) void*)gp,
      (__attribute__((address_space(3))) void*)lp, 16, 0, 0);
}

// cos/sin(pi*j/16), j=0..15 — cover all in-lane FFT16/FFT32 twiddles
__device__ __constant__ float CW16[16] = {
  1.0f, 0.9807852804032304f, 0.9238795325112867f, 0.8314696123025452f,
  0.7071067811865476f, 0.5555702330196022f, 0.3826834323650898f, 0.19509032201612828f,
  0.0f, -0.19509032201612828f, -0.3826834323650898f, -0.5555702330196022f,
  -0.7071067811865476f, -0.8314696123025452f, -0.9238795325112867f, -0.9807852804032304f};
__device__ __constant__ float SW16[16] = {
  0.0f, 0.19509032201612828f, 0.3826834323650898f, 0.5555702330196022f,
  0.7071067811865476f, 0.8314696123025452f, 0.9238795325112867f, 0.9807852804032304f,
  1.0f, 0.9807852804032304f, 0.9238795325112867f, 0.8314696123025452f,
  0.7071067811865476f, 0.5555702330196022f, 0.3826834323650898f, 0.19509032201612828f};
__device__ __constant__ int BR5[32] = {
  0,16,8,24,4,20,12,28,2,18,10,26,6,22,14,30,
  1,17,9,25,5,21,13,29,3,19,11,27,7,23,15,31};

__device__ __forceinline__ int bitrev6(int l) {
  return ((l&1)<<5)|((l&2)<<3)|((l&4)<<1)|((l&8)>>1)|((l&16)>>3)|((l&32)>>5);
}

// hardware sin/cos: input in REVOLUTIONS (angle/2pi); all our args are in [0,1)
__device__ __forceinline__ float hsin(float rev) { return __builtin_amdgcn_sinf(rev); }
__device__ __forceinline__ float hcos(float rev) { return __builtin_amdgcn_cosf(rev); }

// ================= 2048-point cores (fallback path only) =================
__device__ __forceinline__ void fwd_core(float (&ur)[32], float (&ui)[32], const int lane) {
  #pragma unroll
  for (int s = 0; s < 6; ++s) {
    const int h = 32 >> s;
    const int j = lane & (h - 1);
    const float rev = (float)j * (0.5f / (float)h);
    const bool hi = (lane & h) != 0;
    const float c  = hi ? hcos(rev) : 1.0f;
    const float sv = hi ? hsin(rev) : 0.0f;
    const float sgn = hi ? -1.0f : 1.0f;
    #pragma unroll
    for (int r = 0; r < 32; ++r) {
      float pr = __shfl_xor(ur[r], h, 64);
      float pi = __shfl_xor(ui[r], h, 64);
      float tr = fmaf(sgn, ur[r], pr);
      float ti = fmaf(sgn, ui[r], pi);
      ur[r] = fmaf(ti, sv, tr * c);
      ui[r] = fmaf(-tr, sv, ti * c);
    }
  }
  const int kap = bitrev6(lane);
  #pragma unroll
  for (int j = 1; j < 32; ++j) {
    const float rev = (float)(j * kap) * (1.0f / 2048.0f);
    const float sn = hsin(rev), cs = hcos(rev);
    float t = ur[j] * cs + ui[j] * sn;
    ui[j] = ui[j] * cs - ur[j] * sn;
    ur[j] = t;
  }
  #pragma unroll
  for (int s = 0; s < 5; ++s) {
    const int h = 16 >> s;
    #pragma unroll
    for (int i = 0; i < 32; ++i) if (!(i & h)) {
      const int tw = (i & (h - 1)) * (16 / h);
      float dr = ur[i] - ur[i + h], di = ui[i] - ui[i + h];
      ur[i] += ur[i + h]; ui[i] += ui[i + h];
      ur[i + h] = dr * CW16[tw] + di * SW16[tw];
      ui[i + h] = di * CW16[tw] - dr * SW16[tw];
    }
  }
}

__device__ __forceinline__ void inv_core(float (&ur)[32], float (&ui)[32], const int lane) {
  const int kap = bitrev6(lane);
  #pragma unroll
  for (int s = 0; s < 5; ++s) {
    const int h = 1 << s;
    #pragma unroll
    for (int i = 0; i < 32; ++i) if (!(i & h)) {
      const int tw = (i & (h - 1)) * (16 / h);
      float tr2 = ur[i + h] * CW16[tw] - ui[i + h] * SW16[tw];
      float ti2 = ui[i + h] * CW16[tw] + ur[i + h] * SW16[tw];
      ur[i + h] = ur[i] - tr2; ui[i + h] = ui[i] - ti2;
      ur[i] += tr2; ui[i] += ti2;
    }
  }
  #pragma unroll
  for (int j = 1; j < 32; ++j) {
    const float rev = (float)(j * kap) * (1.0f / 2048.0f);
    const float sn = hsin(rev), cs = hcos(rev);
    float t = ur[j] * cs - ui[j] * sn;
    ui[j] = ui[j] * cs + ur[j] * sn;
    ur[j] = t;
  }
  #pragma unroll
  for (int s = 0; s < 6; ++s) {
    const int h = 1 << s;
    const int j = lane & (h - 1);
    const float rev = (float)j * (0.5f / (float)h);
    const bool hi = (lane & h) != 0;
    const float c  = hi ? hcos(rev) : 1.0f;
    const float sv = hi ? hsin(rev) : 0.0f;
    const float sgn = hi ? -1.0f : 1.0f;
    #pragma unroll
    for (int r = 0; r < 32; ++r) {
      float vr = fmaf(-ui[r], sv, ur[r] * c);
      float vi = fmaf(ur[r], sv, ui[r] * c);
      float pvr = __shfl_xor(vr, h, 64);
      float pvi = __shfl_xor(vi, h, 64);
      ur[r] = fmaf(sgn, vr, pvr);
      ui[r] = fmaf(sgn, vi, pvi);
    }
  }
}

// ---------- gate transpose + Hermitian extend + pack (fallback path) ----------
__global__ __launch_bounds__(256) void gate_pack_k(const float* __restrict__ gr,
                                                   const float* __restrict__ gi,
                                                   unsigned int* __restrict__ gt) {
  __shared__ float tr[32][33];
  __shared__ float ti[32][33];
  const int t = threadIdx.x;
  const int k0 = blockIdx.x * 32, hb = blockIdx.y * 32;
  const int hx = t & 31, fr = t >> 5;
  #pragma unroll
  for (int p = 0; p < 4; ++p) {
    int ff = p * 8 + fr;
    int k = k0 + ff;
    int f = (k <= 1024) ? k : (2048 - k);
    float sg = (k <= 1024) ? 1.f : -1.f;
    tr[ff][hx] = gr[(size_t)f * 2048 + hb + hx] * (1.f / 2048.f);
    ti[ff][hx] = sg * gi[(size_t)f * 2048 + hb + hx] * (1.f / 2048.f);
  }
  __syncthreads();
  const int kk = t & 31, hr = t >> 5;
  #pragma unroll
  for (int p = 0; p < 4; ++p) {
    int hl = p * 8 + hr;
    float re = tr[kk][hl], im = ti[kk][hl];
    gt[(size_t)(hb + hl) * 2048 + k0 + kk] =
        (unsigned int)f2bf(re) | ((unsigned int)f2bf(im) << 16);
  }
}

// ---------- A/B table for the rfft path (R12-verified) ----------
__global__ __launch_bounds__(256) void gate_ab_k(const float* __restrict__ gr,
                                                 const float* __restrict__ gi,
                                                 uint2* __restrict__ ab) {
  __shared__ unsigned int uA[32][33];
  __shared__ unsigned int uB[32][33];
  const int t = threadIdx.x;
  const int k0 = blockIdx.x * 32, h0 = blockIdx.y * 32;
  const int c = t & 31, r = t >> 5;
  #pragma unroll
  for (int pp = 0; pp < 4; ++pp) {
    const int kk = pp * 8 + r;
    const int k = k0 + kk;
    const int h = h0 + c;
    const float gkr = gr[(size_t)k * 2048 + h];
    const float gki = gi[(size_t)k * 2048 + h];
    const float gcr = gr[(size_t)(1024 - k) * 2048 + h];
    const float gci = gi[(size_t)(1024 - k) * 2048 + h];
    const float inv = 1.0f / 1024.0f;
    float Ar, Ai, Br, Bi;
    if (k == 0) {
      Ar = (gkr + gcr) * 0.5f * inv; Ai = 0.f;
      Br = 0.f; Bi = (gkr - gcr) * 0.5f * inv;
    } else {
      const float rev = (float)k * (1.0f / 2048.0f);
      const float sn = hsin(rev), cs = hcos(rev);
      const float Sr = (gkr + gcr) * 0.5f, Si = (gki - gci) * 0.5f;
      const float Dr = (gkr - gcr) * 0.5f, Di = (gki + gci) * 0.5f;
      Ar = (Sr - sn * Dr) * inv; Ai = (Si - sn * Di) * inv;
      Br = (-cs * Di) * inv;     Bi = (cs * Dr) * inv;
    }
    uA[kk][c] = pack2bf(Ar, Ai);
    uB[kk][c] = pack2bf(Br, Bi);
  }
  __syncthreads();
  #pragma unroll
  for (int pp = 0; pp < 4; ++pp) {
    const int hh = pp * 8 + r;
    ab[(size_t)(h0 + hh) * 1024 + k0 + c] = make_uint2(uA[c][hh], uB[c][hh]);
  }
}

// ---------- W f32 -> bf16 ----------
__global__ __launch_bounds__(256) void wconv_k(const float* __restrict__ W,
                                               unsigned short* __restrict__ Wb) {
  int i = blockIdx.x * 256 + threadIdx.x;
  float4 v = ((const float4*)W)[i];
  ushort4 o;
  o.x = f2bf(v.x); o.y = f2bf(v.y); o.z = f2bf(v.z); o.w = f2bf(v.w);
  ((ushort4*)Wb)[i] = o;
}

// ---------- T1: x [b,s,h] -> xT [b,h,s], f32 32x32 tiles ----------
__global__ __launch_bounds__(256) void xtrans_k(const float* __restrict__ x,
                                                float* __restrict__ xT) {
  __shared__ float t[32][33];
  const int b = blockIdx.z;
  const int s0 = blockIdx.x * 32, h0 = blockIdx.y * 32;
  const float* xb = x + ((size_t)b * 2048) * 2048;
  float* xTb = xT + ((size_t)b * 2048) * 2048;
  const int c = threadIdx.x & 31, r = threadIdx.x >> 5;
  #pragma unroll
  for (int p = 0; p < 4; ++p) {
    int rr = p * 8 + r;
    t[rr][c] = xb[(size_t)(s0 + rr) * 2048 + h0 + c];
  }
  __syncthreads();
  #pragma unroll
  for (int p = 0; p < 4; ++p) {
    int rr = p * 8 + r;
    xTb[(size_t)(h0 + rr) * 2048 + s0 + c] = t[c][rr];
  }
}

// ---------- T2: yT [b,h,s] -> y [b,s,h], bf16 64x64 tiles ----------
__global__ __launch_bounds__(256) void ytrans_k(const unsigned short* __restrict__ yT,
                                                unsigned short* __restrict__ y) {
  __shared__ unsigned short t[64][66];
  const int b = blockIdx.z;
  const int h0 = blockIdx.x * 64, s0 = blockIdx.y * 64;
  const unsigned short* src = yT + ((size_t)b * 2048 + h0) * 2048 + s0;
  unsigned short* dst = y + ((size_t)b * 2048 + s0) * 2048 + h0;
  const int c = threadIdx.x & 15, r = threadIdx.x >> 4;
  #pragma unroll
  for (int p = 0; p < 4; ++p) {
    int rr = p * 16 + r;
    ushort4 v = *(const ushort4*)(src + (size_t)rr * 2048 + c * 4);
    *(ushort4*)&t[rr][c * 4] = v;
  }
  __syncthreads();
  #pragma unroll
  for (int p = 0; p < 4; ++p) {
    int rr = p * 16 + r;
    ushort4 o;
    o.x = t[c * 4 + 0][rr]; o.y = t[c * 4 + 1][rr];
    o.z = t[c * 4 + 2][rr]; o.w = t[c * 4 + 3][rr];
    *(ushort4*)(dst + (size_t)rr * 2048 + c * 4) = o;
  }
}

// ---------- rfft FFT (R12-verified: 32-reg state, no spill) ----------
__global__ __attribute__((amdgpu_flat_work_group_size(256, 256)))
__attribute__((amdgpu_waves_per_eu(2, 4)))
void fftr_k(const float* __restrict__ xT,
            const uint2* __restrict__ ab,
            unsigned short* __restrict__ yT) {
  __shared__ float snap[4][32];
  const int tid = threadIdx.x;
  const int w = tid >> 6, lane = tid & 63;
  const size_t col = (size_t)blockIdx.x * 4 + w;   // b*2048 + h
  const int h = (int)(col & 2047);

  float ur[16], ui[16];
  const float4* xc = (const float4*)(xT + col * 2048);
  #pragma unroll
  for (int q = 0; q < 8; ++q) {
    float4 v = xc[lane * 8 + q];
    ur[2 * q]     = v.x; ui[2 * q]     = v.y;
    ur[2 * q + 1] = v.z; ui[2 * q + 1] = v.w;
  }

  #pragma unroll
  for (int s = 0; s < 6; ++s) {
    const int hh = 32 >> s;
    const int j = lane & (hh - 1);
    const float rev = (float)j * (0.5f / (float)hh);
    const bool hi = (lane & hh) != 0;
    const float c  = hi ? hcos(rev) : 1.0f;
    const float sv = hi ? hsin(rev) : 0.0f;
    const float sgn = hi ? -1.0f : 1.0f;
    #pragma unroll
    for (int r = 0; r < 16; ++r) {
      float pr = __shfl_xor(ur[r], hh, 64);
      float pi = __shfl_xor(ui[r], hh, 64);
      float tr = fmaf(sgn, ur[r], pr);
      float ti = fmaf(sgn, ui[r], pi);
      ur[r] = fmaf(ti, sv, tr * c);
      ui[r] = fmaf(-tr, sv, ti * c);
    }
  }
  const int kap = bitrev6(lane);
  #pragma unroll
  for (int j = 1; j < 16; ++j) {
    const float rev = (float)(j * kap) * (1.0f / 1024.0f);
    const float sn = hsin(rev), cs = hcos(rev);
    float t = ur[j] * cs + ui[j] * sn;
    ui[j] = ui[j] * cs - ur[j] * sn;
    ur[j] = t;
  }
  #pragma unroll
  for (int s = 0; s < 4; ++s) {
    const int hh = 8 >> s;
    #pragma unroll
    for (int i = 0; i < 16; ++i) if (!(i & hh)) {
      const int tw = (i & (hh - 1)) * (16 / hh);
      float dr = ur[i] - ur[i + hh], di = ui[i] - ui[i + hh];
      ur[i] += ur[i + hh]; ui[i] += ui[i + hh];
      ur[i + hh] = dr * CW16[tw] + di * SW16[tw];
      ui[i + hh] = di * CW16[tw] - dr * SW16[tw];
    }
  }

  if (lane == 0) {
    #pragma unroll
    for (int p = 0; p < 16; ++p) { snap[w][2 * p] = ur[p]; snap[w][2 * p + 1] = ui[p]; }
  }
  const int lsrc = bitrev6((64 - kap) & 63);
  const uint2* abrow = ab + (size_t)h * 1024;
  constexpr int BR4[16]   = {0,8,4,12,2,10,6,14,1,9,5,13,3,11,7,15};
  constexpr int P0L16[16] = {0,1,3,2,7,6,5,4,15,14,13,12,11,10,9,8};
  const bool l0 = (lane == 0);
  #pragma unroll
  for (int p = 0; p < 8; ++p) {
    const int pb = 15 - p;
    float arp = __shfl(ur[pb], lsrc), aip = __shfl(ui[pb], lsrc);
    float arq = __shfl(ur[p], lsrc),  aiq = __shfl(ui[p], lsrc);
    float s0r = snap[w][2 * P0L16[p]],  s0i = snap[w][2 * P0L16[p] + 1];
    float s1r = snap[w][2 * P0L16[pb]], s1i = snap[w][2 * P0L16[pb] + 1];
    arp = l0 ? s0r : arp;  aip = l0 ? s0i : aip;
    arq = l0 ? s1r : arq;  aiq = l0 ? s1i : aiq;
    uint2 gp = abrow[(BR4[p]  << 6) + kap];
    uint2 gq = abrow[(BR4[pb] << 6) + kap];
    {
      float Ar = bflo(gp.x), Ai = bfhi(gp.x), Br = bflo(gp.y), Bi = bfhi(gp.y);
      float zr = ur[p], zi = ui[p];
      ur[p] = Ar * zr - Ai * zi + Br * arp + Bi * aip;
      ui[p] = Ar * zi + Ai * zr + Bi * arp - Br * aip;
    }
    {
      float Ar = bflo(gq.x), Ai = bfhi(gq.x), Br = bflo(gq.y), Bi = bfhi(gq.y);
      float zr = ur[pb], zi = ui[pb];
      ur[pb] = Ar * zr - Ai * zi + Br * arq + Bi * aiq;
      ui[pb] = Ar * zi + Ai * zr + Bi * arq - Br * aiq;
    }
  }

  #pragma unroll
  for (int s = 0; s < 4; ++s) {
    const int hh = 1 << s;
    #pragma unroll
    for (int i = 0; i < 16; ++i) if (!(i & hh)) {
      const int tw = (i & (hh - 1)) * (16 / hh);
      float tr2 = ur[i + hh] * CW16[tw] - ui[i + hh] * SW16[tw];
      float ti2 = ui[i + hh] * CW16[tw] + ur[i + hh] * SW16[tw];
      ur[i + hh] = ur[i] - tr2; ui[i + hh] = ui[i] - ti2;
      ur[i] += tr2; ui[i] += ti2;
    }
  }
  #pragma unroll
  for (int j = 1; j < 16; ++j) {
    const float rev = (float)(j * kap) * (1.0f / 1024.0f);
    const float sn = hsin(rev), cs = hcos(rev);
    float t = ur[j] * cs - ui[j] * sn;
    ui[j] = ui[j] * cs + ur[j] * sn;
    ur[j] = t;
  }
  #pragma unroll
  for (int s = 0; s < 6; ++s) {
    const int hh = 1 << s;
    const int j = lane & (hh - 1);
    const float rev = (float)j * (0.5f / (float)hh);
    const bool hi = (lane & hh) != 0;
    const float c  = hi ? hcos(rev) : 1.0f;
    const float sv = hi ? hsin(rev) : 0.0f;
    const float sgn = hi ? -1.0f : 1.0f;
    #pragma unroll
    for (int r = 0; r < 16; ++r) {
      float vr = fmaf(-ui[r], sv, ur[r] * c);
      float vi = fmaf(ur[r], sv, ui[r] * c);
      float pvr = __shfl_xor(vr, hh, 64);
      float pvi = __shfl_xor(vi, hh, 64);
      ur[r] = fmaf(sgn, vr, pvr);
      ui[r] = fmaf(sgn, vi, pvi);
    }
  }

  uint4* dst = (uint4*)(yT + col * 2048) + lane * 4;
  #pragma unroll
  for (int g = 0; g < 4; ++g) {
    uint4 o;
    o.x = pack2bf(ur[4 * g + 0], ui[4 * g + 0]);
    o.y = pack2bf(ur[4 * g + 1], ui[4 * g + 1]);
    o.z = pack2bf(ur[4 * g + 2], ui[4 * g + 2]);
    o.w = pack2bf(ur[4 * g + 3], ui[4 * g + 3]);
    dst[g] = o;
  }
}

// ---------- fallback (R3-proven): FFT-2048 reading x directly via LDS staging ----------
__global__ __attribute__((amdgpu_flat_work_group_size(512, 512)))
__attribute__((amdgpu_waves_per_eu(2, 4)))
void fft_gate_k(const float* __restrict__ x,
                const unsigned int* __restrict__ gt,
                unsigned short* __restrict__ y) {
  __shared__ float lds[8 * 516];
  const int tid = threadIdx.x;
  const int w = tid >> 6;
  const int lane = tid & 63;
  const int bid = blockIdx.x;
  const int swz = (bid & 7) * 256 + (bid >> 3);
  const int h0 = (swz & 255) << 3;
  const int b = swz >> 8;
  const int hh = tid & 7, srow = tid >> 3;

  float ur[32], ui[32];
  const size_t xbase = ((size_t)b * 2048) * 2048 + h0;

  for (int c = 0; c < 4; ++c) {
    #pragma unroll
    for (int q = 0; q < 8; ++q) {
      int soff = q * 64 + srow;
      float v = x[xbase + (size_t)(c * 512 + soff) * 2048 + hh];
      lds[hh * 516 + (soff ^ ((soff >> 5) & 15))] = v;
    }
    __syncthreads();
    if ((lane >> 4) == c) {
      const int li = lane & 15;
      #pragma unroll
      for (int j = 0; j < 32; ++j) {
        ur[j] = lds[w * 516 + ((32 * li + j) ^ li)];
        ui[j] = 0.f;
      }
    }
    __syncthreads();
  }

  fwd_core(ur, ui, lane);
  {
    const int kap = bitrev6(lane);
    const unsigned int* grow = gt + (size_t)(h0 + w) * 2048;
    #pragma unroll
    for (int p = 0; p < 32; ++p) {
      unsigned int g = grow[(BR5[p] << 6) + kap];
      float gre = bflo(g), gim = bfhi(g);
      float t = ur[p] * gre - ui[p] * gim;
      ui[p] = ur[p] * gim + ui[p] * gre;
      ur[p] = t;
    }
  }
  inv_core(ur, ui, lane);

  for (int c = 0; c < 4; ++c) {
    if ((lane >> 4) == c) {
      const int li = lane & 15;
      #pragma unroll
      for (int r = 0; r < 32; ++r)
        lds[w * 516 + ((32 * li + r) ^ li)] = ur[r];
    }
    __syncthreads();
    #pragma unroll
    for (int q = 0; q < 8; ++q) {
      int soff = q * 64 + srow;
      float v = lds[hh * 516 + (soff ^ ((soff >> 5) & 15))];
      y[xbase + (size_t)(c * 512 + soff) * 2048 + hh] = f2bf(v);
    }
    __syncthreads();
  }
}

// ---------- GEMM fallback: m97-style 128x128 tile ----------
__global__ __launch_bounds__(256) void gemm_k(const unsigned short* __restrict__ A,
                                              const unsigned short* __restrict__ Bw,
                                              const float* __restrict__ bias,
                                              float* __restrict__ C) {
  __shared__ unsigned short sA[128 * 32];
  __shared__ unsigned short sB[128 * 32];
  const int tid = threadIdx.x;
  const int nwg = gridDim.x;
  const int cpx = nwg >> 3;
  const int bid = blockIdx.x;
  const int swz = (bid & 7) * cpx + (bid >> 3);
  const int bm = swz >> 4, bn = swz & 15;
  const int m0 = bm << 7, n0 = bn << 7;
  const int w = tid >> 6, lane = tid & 63;
  const int arow = tid >> 2, koff = (tid & 3) << 3;
  const unsigned short* gA = A + (size_t)(m0 + arow) * 2048 + koff;
  const unsigned short* gB = Bw + (size_t)(n0 + arow) * 2048 + koff;
  char* sAb = (char*)sA + w * 1024;
  char* sBb = (char*)sB + w * 1024;

  f32x4 acc[4][4];
  #pragma unroll
  for (int i = 0; i < 4; ++i)
    #pragma unroll
    for (int j = 0; j < 4; ++j) acc[i][j] = (f32x4){0.f, 0.f, 0.f, 0.f};

  const int wr = w >> 1, wc = w & 1;
  const int row16 = lane & 15, kb = lane >> 4;

  for (int k0 = 0; k0 < 2048; k0 += 32) {
    glds16(gA + k0, sAb);
    glds16(gA + 64 * 2048 + k0, sAb + 4096);
    glds16(gB + k0, sBb);
    glds16(gB + 64 * 2048 + k0, sBb + 4096);
    __syncthreads();
    bf16x8 af[4], bfr[4];
    #pragma unroll
    for (int i = 0; i < 4; ++i) {
      int r = (wr << 6) + (i << 4) + row16;
      af[i] = *(const bf16x8*)(sA + r * 32 + (kb << 3));
    }
    #pragma unroll
    for (int j2 = 0; j2 < 4; ++j2) {
      int r = (wc << 6) + (j2 << 4) + row16;
      bfr[j2] = *(const bf16x8*)(sB + r * 32 + (kb << 3));
    }
    #pragma unroll
    for (int i = 0; i < 4; ++i)
      #pragma unroll
      for (int j2 = 0; j2 < 4; ++j2)
        acc[i][j2] = __builtin_amdgcn_mfma_f32_16x16x32_bf16(af[i], bfr[j2], acc[i][j2], 0, 0, 0);
    __syncthreads();
  }

  const int rq = lane >> 4;
  #pragma unroll
  for (int j2 = 0; j2 < 4; ++j2) {
    int oc = n0 + (wc << 6) + (j2 << 4) + row16;
    float bj = bias[oc];
    #pragma unroll
    for (int i = 0; i < 4; ++i) {
      int mr = m0 + (wr << 6) + (i << 4) + (rq << 2);
      #pragma unroll
      for (int q = 0; q < 4; ++q)
        C[(size_t)(mr + q) * 2048 + oc] = acc[i][j2][q] + bj;
    }
  }
}

// ---------- GEMM main: 256x256 tile, 4-stage pipeline, 2-phase K-step + setprio ----------
// R12 counters: MfmaUtil 37.6%, 0 bank conflicts, ~2870 cyc/K-step vs 1030
// ideal -> the monolithic {12 ds_read; 32 MFMA; vmcnt; barrier} step has no
// wave role-diversity. Split each K-step into two 16-MFMA phases, each
// {ds_read subtile || issue half-STAGE -> lgkmcnt(0)+sched_barrier (rule #18)
// -> setprio(1) MFMA setprio(0) -> barrier}; counted vmcnt(8) only at phase 2
// (T3 gates T5 per the regime table; counted vmcnt = T4, never drain to 0).
// Pipeline safety unchanged: STAGE(t+3) issued after iter t-1's barrier, by
// which time buffer (t+3)&3's last readers (iter t-1) have retired.
__global__ __launch_bounds__(512) void gemm8_k(const unsigned short* __restrict__ A,
                                               const unsigned short* __restrict__ Bw,
                                               const float* __restrict__ bias,
                                               float* __restrict__ C) {
  extern __shared__ char lds[];   // 4 x (A 16KB + B 16KB) = 128 KiB
  const int tid = threadIdx.x;
  const int w = tid >> 6, lane = tid & 63;
  const int bid = blockIdx.x;
  const int swz = (bid & 7) * 64 + (bid >> 3);   // 512 wgs, 8 XCDs, bijective
  const int m0 = (swz >> 3) << 8;
  const int n0 = (swz & 7) << 8;
  const int wr = w >> 2, wc = w & 3;
  const int row16 = lane & 15, kb = lane >> 4;

  const int lr = lane >> 2, ls = lane & 3;
  const int r0 = (w << 5) + lr, r1 = r0 + 16;
  const unsigned short* pA0 = A  + (size_t)(m0 + r0) * 2048 + ((ls ^ ((r0 >> 1) & 3)) << 3);
  const unsigned short* pA1 = A  + (size_t)(m0 + r1) * 2048 + ((ls ^ ((r1 >> 1) & 3)) << 3);
  const unsigned short* pB0 = Bw + (size_t)(n0 + r0) * 2048 + ((ls ^ ((r0 >> 1) & 3)) << 3);
  const unsigned short* pB1 = Bw + (size_t)(n0 + r1) * 2048 + ((ls ^ ((r1 >> 1) & 3)) << 3);
  const int dW = w << 11;

  f32x4 acc[8][4];
  #pragma unroll
  for (int i = 0; i < 8; ++i)
    #pragma unroll
    for (int j = 0; j < 4; ++j) acc[i][j] = (f32x4){0.f, 0.f, 0.f, 0.f};

  auto STAGE_A = [&](int t) {
    char* base = lds + ((t & 3) << 15);
    const int k0 = t << 5;
    glds16(pA0 + k0, base + dW);
    glds16(pA1 + k0, base + dW + 1024);
  };
  auto STAGE_B = [&](int t) {
    char* base = lds + ((t & 3) << 15);
    const int k0 = t << 5;
    glds16(pB0 + k0, base + 16384 + dW);
    glds16(pB1 + k0, base + 16384 + dW + 1024);
  };
  auto LDA4 = [&](const char* base, int i0, bf16x8 (&af)[4]) {
    #pragma unroll
    for (int i = 0; i < 4; ++i) {
      const int r = (wr << 7) + ((i0 + i) << 4) + row16;
      af[i] = *(const bf16x8*)(base + (r << 6) + ((kb ^ ((r >> 1) & 3)) << 4));
    }
  };
  auto LDB4 = [&](const char* base, bf16x8 (&bfr)[4]) {
    #pragma unroll
    for (int j = 0; j < 4; ++j) {
      const int r = (wc << 6) + (j << 4) + row16;
      bfr[j] = *(const bf16x8*)(base + 16384 + (r << 6) + ((kb ^ ((r >> 1) & 3)) << 4));
    }
  };
  auto MM16 = [&](const bf16x8 (&af)[4], const bf16x8 (&bfr)[4], int i0) {
    #pragma unroll
    for (int i = 0; i < 4; ++i)
      #pragma unroll
      for (int j = 0; j < 4; ++j)
        acc[i0 + i][j] = __builtin_amdgcn_mfma_f32_16x16x32_bf16(af[i], bfr[j], acc[i0 + i][j], 0, 0, 0);
  };
  auto COMPUTE = [&](int t) {   // monolithic form, used for the tail only
    const char* base = lds + ((t & 3) << 15);
    bf16x8 af[4], af2[4], bfr[4];
    LDA4(base, 0, af); LDA4(base, 4, af2); LDB4(base, bfr);
    MM16(af, bfr, 0); MM16(af2, bfr, 4);
  };

  // prologue: stage tiles 0..2 (both halves); wait tile 0
  STAGE_A(0); STAGE_B(0); STAGE_A(1); STAGE_B(1); STAGE_A(2); STAGE_B(2);
  asm volatile("s_waitcnt vmcnt(8)" ::: "memory");
  __builtin_amdgcn_s_barrier();
  __builtin_amdgcn_sched_barrier(0);

  for (int t = 0; t < 61; ++t) {
    const char* base = lds + ((t & 3) << 15);
    // ---- phase 1: A-rows 0..3 x all B; issue A-half of t+3 ----
    bf16x8 af[4], bfr[4];
    LDA4(base, 0, af);
    LDB4(base, bfr);
    STAGE_A(t + 3);
    asm volatile("s_waitcnt lgkmcnt(0)" ::: "memory");
    __builtin_amdgcn_sched_barrier(0);      // rule #18: pin MFMA after lgkmcnt
    __builtin_amdgcn_s_setprio(1);
    MM16(af, bfr, 0);
    __builtin_amdgcn_s_setprio(0);
    __builtin_amdgcn_s_barrier();
    // ---- phase 2: A-rows 4..7 x all B; issue B-half of t+3 ----
    bf16x8 af2[4];
    LDA4(base, 4, af2);
    STAGE_B(t + 3);
    asm volatile("s_waitcnt lgkmcnt(0)" ::: "memory");
    __builtin_amdgcn_sched_barrier(0);
    __builtin_amdgcn_s_setprio(1);
    MM16(af2, bfr, 4);
    __builtin_amdgcn_s_setprio(0);
    asm volatile("s_waitcnt vmcnt(8)" ::: "memory");   // tile t+1 landed
    __builtin_amdgcn_s_barrier();
    __builtin_amdgcn_sched_barrier(0);
  }
  COMPUTE(61);
  asm volatile("s_waitcnt vmcnt(4)" ::: "memory");
  __builtin_amdgcn_s_barrier();
  __builtin_amdgcn_sched_barrier(0);
  COMPUTE(62);
  asm volatile("s_waitcnt vmcnt(0)" ::: "memory");
  __builtin_amdgcn_s_barrier();
  __builtin_amdgcn_sched_barrier(0);
  COMPUTE(63);

  const int rq = lane >> 4;
  #pragma unroll
  for (int j = 0; j < 4; ++j) {
    const int oc = n0 + (wc << 6) + (j << 4) + row16;
    const float bj = bias[oc];
    #pragma unroll
    for (int i = 0; i < 8; ++i) {
      const int mr = m0 + (wr << 7) + (i << 4) + (rq << 2);
      #pragma unroll
      for (int q = 0; q < 4; ++q)
        C[(size_t)(mr + q) * 2048 + oc] = acc[i][j][q] + bj;
    }
  }
}

extern "C" void kernel_launch(void* const* d_in, const int* in_sizes, int n_in,
                              void* d_out, int out_size, void* d_ws, size_t ws_size,
                              hipStream_t stream) {
  const float* x  = (const float*)d_in[0];
  const float* gr = (const float*)d_in[1];
  const float* gi = (const float*)d_in[2];
  const float* W  = (const float*)d_in[3];
  const float* bs = (const float*)d_in[4];
  float* out = (float*)d_out;

  char* ws = (char*)d_ws;
  unsigned short* yb = (unsigned short*)ws;                          // 64 MB  y bf16 [b,s,h]
  unsigned short* Wb = (unsigned short*)(ws + (64ull << 20));        // 8 MB   W bf16
  unsigned int*   gt = (unsigned int*)(ws + (72ull << 20));          // 16 MB  gate (fallback)
  uint2*          ab = (uint2*)(ws + (72ull << 20));                 // 16 MB  A/B table (fast)
  float*          xT = (float*)(ws + (88ull << 20));                 // 128 MB x transposed [b,h,s]
  unsigned short* yT = (unsigned short*)(ws + (216ull << 20));       // 64 MB  y transposed [b,h,s]
  const bool fast = ws_size >= (280ull << 20);

  hipLaunchKernelGGL(wconv_k, dim3(4096), dim3(256), 0, stream, W, Wb);
  if (fast) {
    hipLaunchKernelGGL(gate_ab_k, dim3(32, 64), dim3(256), 0, stream, gr, gi, ab);
    hipLaunchKernelGGL(xtrans_k, dim3(64, 64, 8), dim3(256), 0, stream, x, xT);
    hipLaunchKernelGGL(fftr_k, dim3(4096), dim3(256), 0, stream, xT, ab, yT);
    hipLaunchKernelGGL(ytrans_k, dim3(32, 32, 8), dim3(256), 0, stream, yT, yb);
  } else {
    hipLaunchKernelGGL(gate_pack_k, dim3(64, 64), dim3(256), 0, stream, gr, gi, gt);
    hipLaunchKernelGGL(fft_gate_k, dim3(2048), dim3(512), 0, stream, x, gt, yb);
  }

  const bool big = hipFuncSetAttribute((const void*)gemm8_k,
                                       hipFuncAttributeMaxDynamicSharedMemorySize,
                                       131072) == hipSuccess;
  if (big) {
    hipLaunchKernelGGL(gemm8_k, dim3(512), dim3(512), 131072, stream, yb, Wb, bs, out);
  } else {
    hipLaunchKernelGGL(gemm_k, dim3(2048), dim3(256), 0, stream, yb, Wb, bs, out);
  }
}

// Round 15
// 350.146 us; speedup vs baseline: 1.5348x; 1.0480x over previous
//
#include <hip/hip_runtime.h>
#include <math.h>

typedef __attribute__((ext_vector_type(8))) short bf16x8;
typedef __attribute__((ext_vector_type(4))) float f32x4;

__device__ __forceinline__ unsigned short f2bf(float f) {
  unsigned int u = __float_as_uint(f);
  unsigned int r = (u + 0x7fffu + ((u >> 16) & 1u)) >> 16;
  return (unsigned short)r;
}
__device__ __forceinline__ unsigned int pack2bf(float a, float b) {
  return (unsigned int)f2bf(a) | ((unsigned int)f2bf(b) << 16);
}
__device__ __forceinline__ float bflo(unsigned int g) { return __uint_as_float(g << 16); }
__device__ __forceinline__ float bfhi(unsigned int g) { return __uint_as_float(g & 0xffff0000u); }

__device__ __forceinline__ void glds16(const void* gp, void* lp) {
  __builtin_amdgcn_global_load_lds(
      (const __attribute__((address_space(1))) void*)gp,
      (__attribute__((address_space(3))) void*)lp, 16, 0, 0);
}

// cos/sin(pi*j/16), j=0..15 — cover all in-lane FFT16/FFT32 twiddles
__device__ __constant__ float CW16[16] = {
  1.0f, 0.9807852804032304f, 0.9238795325112867f, 0.8314696123025452f,
  0.7071067811865476f, 0.5555702330196022f, 0.3826834323650898f, 0.19509032201612828f,
  0.0f, -0.19509032201612828f, -0.3826834323650898f, -0.5555702330196022f,
  -0.7071067811865476f, -0.8314696123025452f, -0.9238795325112867f, -0.9807852804032304f};
__device__ __constant__ float SW16[16] = {
  0.0f, 0.19509032201612828f, 0.3826834323650898f, 0.5555702330196022f,
  0.7071067811865476f, 0.8314696123025452f, 0.9238795325112867f, 0.9807852804032304f,
  1.0f, 0.9807852804032304f, 0.9238795325112867f, 0.8314696123025452f,
  0.7071067811865476f, 0.5555702330196022f, 0.3826834323650898f, 0.19509032201612828f};
__device__ __constant__ int BR5[32] = {
  0,16,8,24,4,20,12,28,2,18,10,26,6,22,14,30,
  1,17,9,25,5,21,13,29,3,19,11,27,7,23,15,31};

__device__ __forceinline__ int bitrev6(int l) {
  return ((l&1)<<5)|((l&2)<<3)|((l&4)<<1)|((l&8)>>1)|((l&16)>>3)|((l&32)>>5);
}

// hardware sin/cos: input in REVOLUTIONS (angle/2pi); all our args are in [0,1)
__device__ __forceinline__ float hsin(float rev) { return __builtin_amdgcn_sinf(rev); }
__device__ __forceinline__ float hcos(float rev) { return __builtin_amdgcn_cosf(rev); }

// ================= 2048-point cores (fallback path only) =================
__device__ __forceinline__ void fwd_core(float (&ur)[32], float (&ui)[32], const int lane) {
  #pragma unroll
  for (int s = 0; s < 6; ++s) {
    const int h = 32 >> s;
    const int j = lane & (h - 1);
    const float rev = (float)j * (0.5f / (float)h);
    const bool hi = (lane & h) != 0;
    const float c  = hi ? hcos(rev) : 1.0f;
    const float sv = hi ? hsin(rev) : 0.0f;
    const float sgn = hi ? -1.0f : 1.0f;
    #pragma unroll
    for (int r = 0; r < 32; ++r) {
      float pr = __shfl_xor(ur[r], h, 64);
      float pi = __shfl_xor(ui[r], h, 64);
      float tr = fmaf(sgn, ur[r], pr);
      float ti = fmaf(sgn, ui[r], pi);
      ur[r] = fmaf(ti, sv, tr * c);
      ui[r] = fmaf(-tr, sv, ti * c);
    }
  }
  const int kap = bitrev6(lane);
  #pragma unroll
  for (int j = 1; j < 32; ++j) {
    const float rev = (float)(j * kap) * (1.0f / 2048.0f);
    const float sn = hsin(rev), cs = hcos(rev);
    float t = ur[j] * cs + ui[j] * sn;
    ui[j] = ui[j] * cs - ur[j] * sn;
    ur[j] = t;
  }
  #pragma unroll
  for (int s = 0; s < 5; ++s) {
    const int h = 16 >> s;
    #pragma unroll
    for (int i = 0; i < 32; ++i) if (!(i & h)) {
      const int tw = (i & (h - 1)) * (16 / h);
      float dr = ur[i] - ur[i + h], di = ui[i] - ui[i + h];
      ur[i] += ur[i + h]; ui[i] += ui[i + h];
      ur[i + h] = dr * CW16[tw] + di * SW16[tw];
      ui[i + h] = di * CW16[tw] - dr * SW16[tw];
    }
  }
}

__device__ __forceinline__ void inv_core(float (&ur)[32], float (&ui)[32], const int lane) {
  const int kap = bitrev6(lane);
  #pragma unroll
  for (int s = 0; s < 5; ++s) {
    const int h = 1 << s;
    #pragma unroll
    for (int i = 0; i < 32; ++i) if (!(i & h)) {
      const int tw = (i & (h - 1)) * (16 / h);
      float tr2 = ur[i + h] * CW16[tw] - ui[i + h] * SW16[tw];
      float ti2 = ui[i + h] * CW16[tw] + ur[i + h] * SW16[tw];
      ur[i + h] = ur[i] - tr2; ui[i + h] = ui[i] - ti2;
      ur[i] += tr2; ui[i] += ti2;
    }
  }
  #pragma unroll
  for (int j = 1; j < 32; ++j) {
    const float rev = (float)(j * kap) * (1.0f / 2048.0f);
    const float sn = hsin(rev), cs = hcos(rev);
    float t = ur[j] * cs - ui[j] * sn;
    ui[j] = ui[j] * cs + ur[j] * sn;
    ur[j] = t;
  }
  #pragma unroll
  for (int s = 0; s < 6; ++s) {
    const int h = 1 << s;
    const int j = lane & (h - 1);
    const float rev = (float)j * (0.5f / (float)h);
    const bool hi = (lane & h) != 0;
    const float c  = hi ? hcos(rev) : 1.0f;
    const float sv = hi ? hsin(rev) : 0.0f;
    const float sgn = hi ? -1.0f : 1.0f;
    #pragma unroll
    for (int r = 0; r < 32; ++r) {
      float vr = fmaf(-ui[r], sv, ur[r] * c);
      float vi = fmaf(ur[r], sv, ui[r] * c);
      float pvr = __shfl_xor(vr, h, 64);
      float pvi = __shfl_xor(vi, h, 64);
      ur[r] = fmaf(sgn, vr, pvr);
      ui[r] = fmaf(sgn, vi, pvi);
    }
  }
}

// ---------- gate transpose + Hermitian extend + pack (fallback path) ----------
__global__ __launch_bounds__(256) void gate_pack_k(const float* __restrict__ gr,
                                                   const float* __restrict__ gi,
                                                   unsigned int* __restrict__ gt) {
  __shared__ float tr[32][33];
  __shared__ float ti[32][33];
  const int t = threadIdx.x;
  const int k0 = blockIdx.x * 32, hb = blockIdx.y * 32;
  const int hx = t & 31, fr = t >> 5;
  #pragma unroll
  for (int p = 0; p < 4; ++p) {
    int ff = p * 8 + fr;
    int k = k0 + ff;
    int f = (k <= 1024) ? k : (2048 - k);
    float sg = (k <= 1024) ? 1.f : -1.f;
    tr[ff][hx] = gr[(size_t)f * 2048 + hb + hx] * (1.f / 2048.f);
    ti[ff][hx] = sg * gi[(size_t)f * 2048 + hb + hx] * (1.f / 2048.f);
  }
  __syncthreads();
  const int kk = t & 31, hr = t >> 5;
  #pragma unroll
  for (int p = 0; p < 4; ++p) {
    int hl = p * 8 + hr;
    float re = tr[kk][hl], im = ti[kk][hl];
    gt[(size_t)(hb + hl) * 2048 + k0 + kk] =
        (unsigned int)f2bf(re) | ((unsigned int)f2bf(im) << 16);
  }
}

// ---------- A/B table for the rfft path (R12-verified) ----------
__global__ __launch_bounds__(256) void gate_ab_k(const float* __restrict__ gr,
                                                 const float* __restrict__ gi,
                                                 uint2* __restrict__ ab) {
  __shared__ unsigned int uA[32][33];
  __shared__ unsigned int uB[32][33];
  const int t = threadIdx.x;
  const int k0 = blockIdx.x * 32, h0 = blockIdx.y * 32;
  const int c = t & 31, r = t >> 5;
  #pragma unroll
  for (int pp = 0; pp < 4; ++pp) {
    const int kk = pp * 8 + r;
    const int k = k0 + kk;
    const int h = h0 + c;
    const float gkr = gr[(size_t)k * 2048 + h];
    const float gki = gi[(size_t)k * 2048 + h];
    const float gcr = gr[(size_t)(1024 - k) * 2048 + h];
    const float gci = gi[(size_t)(1024 - k) * 2048 + h];
    const float inv = 1.0f / 1024.0f;
    float Ar, Ai, Br, Bi;
    if (k == 0) {
      Ar = (gkr + gcr) * 0.5f * inv; Ai = 0.f;
      Br = 0.f; Bi = (gkr - gcr) * 0.5f * inv;
    } else {
      const float rev = (float)k * (1.0f / 2048.0f);
      const float sn = hsin(rev), cs = hcos(rev);
      const float Sr = (gkr + gcr) * 0.5f, Si = (gki - gci) * 0.5f;
      const float Dr = (gkr - gcr) * 0.5f, Di = (gki + gci) * 0.5f;
      Ar = (Sr - sn * Dr) * inv; Ai = (Si - sn * Di) * inv;
      Br = (-cs * Di) * inv;     Bi = (cs * Dr) * inv;
    }
    uA[kk][c] = pack2bf(Ar, Ai);
    uB[kk][c] = pack2bf(Br, Bi);
  }
  __syncthreads();
  #pragma unroll
  for (int pp = 0; pp < 4; ++pp) {
    const int hh = pp * 8 + r;
    ab[(size_t)(h0 + hh) * 1024 + k0 + c] = make_uint2(uA[c][hh], uB[c][hh]);
  }
}

// ---------- W f32 -> bf16 ----------
__global__ __launch_bounds__(256) void wconv_k(const float* __restrict__ W,
                                               unsigned short* __restrict__ Wb) {
  int i = blockIdx.x * 256 + threadIdx.x;
  float4 v = ((const float4*)W)[i];
  ushort4 o;
  o.x = f2bf(v.x); o.y = f2bf(v.y); o.z = f2bf(v.z); o.w = f2bf(v.w);
  ((ushort4*)Wb)[i] = o;
}

// ---------- T1: x [b,s,h] -> xT [b,h,s], f32 32x32 tiles ----------
__global__ __launch_bounds__(256) void xtrans_k(const float* __restrict__ x,
                                                float* __restrict__ xT) {
  __shared__ float t[32][33];
  const int b = blockIdx.z;
  const int s0 = blockIdx.x * 32, h0 = blockIdx.y * 32;
  const float* xb = x + ((size_t)b * 2048) * 2048;
  float* xTb = xT + ((size_t)b * 2048) * 2048;
  const int c = threadIdx.x & 31, r = threadIdx.x >> 5;
  #pragma unroll
  for (int p = 0; p < 4; ++p) {
    int rr = p * 8 + r;
    t[rr][c] = xb[(size_t)(s0 + rr) * 2048 + h0 + c];
  }
  __syncthreads();
  #pragma unroll
  for (int p = 0; p < 4; ++p) {
    int rr = p * 8 + r;
    xTb[(size_t)(h0 + rr) * 2048 + s0 + c] = t[c][rr];
  }
}

// ---------- T2: yT [b,h,s] -> y [b,s,h], bf16 64x64 tiles ----------
__global__ __launch_bounds__(256) void ytrans_k(const unsigned short* __restrict__ yT,
                                                unsigned short* __restrict__ y) {
  __shared__ unsigned short t[64][66];
  const int b = blockIdx.z;
  const int h0 = blockIdx.x * 64, s0 = blockIdx.y * 64;
  const unsigned short* src = yT + ((size_t)b * 2048 + h0) * 2048 + s0;
  unsigned short* dst = y + ((size_t)b * 2048 + s0) * 2048 + h0;
  const int c = threadIdx.x & 15, r = threadIdx.x >> 4;
  #pragma unroll
  for (int p = 0; p < 4; ++p) {
    int rr = p * 16 + r;
    ushort4 v = *(const ushort4*)(src + (size_t)rr * 2048 + c * 4);
    *(ushort4*)&t[rr][c * 4] = v;
  }
  __syncthreads();
  #pragma unroll
  for (int p = 0; p < 4; ++p) {
    int rr = p * 16 + r;
    ushort4 o;
    o.x = t[c * 4 + 0][rr]; o.y = t[c * 4 + 1][rr];
    o.z = t[c * 4 + 2][rr]; o.w = t[c * 4 + 3][rr];
    *(ushort4*)(dst + (size_t)rr * 2048 + c * 4) = o;
  }
}

// ---------- rfft FFT: one wave per column; z[n]=x[2n]+i*x[2n+1], FFT-1024 ----------
// R14: (1) ALL 16 ab-table loads issued up-front (depend only on h) — they
// hide under the entire forward FFT and arrive as registers; (2) gate loop
// chunked 2x4 with sched_barrier so the 32 shfl partner-gathers can't be
// mass-hoisted (R7-proven: unrolled gather hoisting was the spill source).
// Peak demand ~100 regs < 128 cap.
__global__ __attribute__((amdgpu_flat_work_group_size(256, 256)))
__attribute__((amdgpu_waves_per_eu(2, 4)))
void fftr_k(const float* __restrict__ xT,
            const uint2* __restrict__ ab,
            unsigned short* __restrict__ yT) {
  __shared__ float snap[4][32];
  const int tid = threadIdx.x;
  const int w = tid >> 6, lane = tid & 63;
  const size_t col = (size_t)blockIdx.x * 4 + w;   // b*2048 + h
  const int h = (int)(col & 2047);
  const int kap = bitrev6(lane);
  constexpr int BR4[16]   = {0,8,4,12,2,10,6,14,1,9,5,13,3,11,7,15};
  constexpr int P0L16[16] = {0,1,3,2,7,6,5,4,15,14,13,12,11,10,9,8};

  // ---- issue x loads, then ab loads (both in flight together) ----
  const float4* xc = (const float4*)(xT + col * 2048);
  float4 xv[8];
  #pragma unroll
  for (int q = 0; q < 8; ++q) xv[q] = xc[lane * 8 + q];
  const uint2* abrow = ab + (size_t)h * 1024;
  uint2 abv[16];
  #pragma unroll
  for (int p = 0; p < 16; ++p) abv[p] = abrow[(BR4[p] << 6) + kap];

  float ur[16], ui[16];
  #pragma unroll
  for (int q = 0; q < 8; ++q) {
    ur[2 * q]     = xv[q].x; ui[2 * q]     = xv[q].y;
    ur[2 * q + 1] = xv[q].z; ui[2 * q + 1] = xv[q].w;
  }

  // ---- forward cross-lane DIF-64 (branchless) ----
  #pragma unroll
  for (int s = 0; s < 6; ++s) {
    const int hh = 32 >> s;
    const int j = lane & (hh - 1);
    const float rev = (float)j * (0.5f / (float)hh);
    const bool hi = (lane & hh) != 0;
    const float c  = hi ? hcos(rev) : 1.0f;
    const float sv = hi ? hsin(rev) : 0.0f;
    const float sgn = hi ? -1.0f : 1.0f;
    #pragma unroll
    for (int r = 0; r < 16; ++r) {
      float pr = __shfl_xor(ur[r], hh, 64);
      float pi = __shfl_xor(ui[r], hh, 64);
      float tr = fmaf(sgn, ur[r], pr);
      float ti = fmaf(sgn, ui[r], pi);
      ur[r] = fmaf(ti, sv, tr * c);
      ui[r] = fmaf(-tr, sv, ti * c);
    }
  }
  // ---- forward mid-twiddle e^{-2pi i j kap/1024} ----
  #pragma unroll
  for (int j = 1; j < 16; ++j) {
    const float rev = (float)(j * kap) * (1.0f / 1024.0f);
    const float sn = hsin(rev), cs = hcos(rev);
    float t = ur[j] * cs + ui[j] * sn;
    ui[j] = ui[j] * cs - ur[j] * sn;
    ur[j] = t;
  }
  // ---- in-lane DIF-16 ----
  #pragma unroll
  for (int s = 0; s < 4; ++s) {
    const int hh = 8 >> s;
    #pragma unroll
    for (int i = 0; i < 16; ++i) if (!(i & hh)) {
      const int tw = (i & (hh - 1)) * (16 / hh);
      float dr = ur[i] - ur[i + hh], di = ui[i] - ui[i + hh];
      ur[i] += ur[i + hh]; ui[i] += ui[i + hh];
      ur[i + hh] = dr * CW16[tw] + di * SW16[tw];
      ui[i + hh] = di * CW16[tw] - dr * SW16[tw];
    }
  }

  // ---- gate: Z'[k] = A Z[k] + B conj(Z[1024-k]) ----
  if (lane == 0) {
    #pragma unroll
    for (int p = 0; p < 16; ++p) { snap[w][2 * p] = ur[p]; snap[w][2 * p + 1] = ui[p]; }
  }
  const int lsrc = bitrev6((64 - kap) & 63);
  const bool l0 = (lane == 0);
  #pragma unroll
  for (int c2 = 0; c2 < 4; ++c2) {
    __builtin_amdgcn_sched_barrier(0);   // cap shfl/snap hoisting to one chunk
    #pragma unroll
    for (int pp = 0; pp < 2; ++pp) {
      const int p = c2 * 2 + pp;
      const int pb = 15 - p;
      float arp = __shfl(ur[pb], lsrc), aip = __shfl(ui[pb], lsrc);  // partner of reg p
      float arq = __shfl(ur[p], lsrc),  aiq = __shfl(ui[p], lsrc);   // partner of reg pb
      float s0r = snap[w][2 * P0L16[p]],  s0i = snap[w][2 * P0L16[p] + 1];
      float s1r = snap[w][2 * P0L16[pb]], s1i = snap[w][2 * P0L16[pb] + 1];
      arp = l0 ? s0r : arp;  aip = l0 ? s0i : aip;
      arq = l0 ? s1r : arq;  aiq = l0 ? s1i : aiq;
      {
        float Ar = bflo(abv[p].x), Ai = bfhi(abv[p].x);
        float Br = bflo(abv[p].y), Bi = bfhi(abv[p].y);
        float zr = ur[p], zi = ui[p];
        ur[p] = Ar * zr - Ai * zi + Br * arp + Bi * aip;
        ui[p] = Ar * zi + Ai * zr + Bi * arp - Br * aip;
      }
      {
        float Ar = bflo(abv[pb].x), Ai = bfhi(abv[pb].x);
        float Br = bflo(abv[pb].y), Bi = bfhi(abv[pb].y);
        float zr = ur[pb], zi = ui[pb];
        ur[pb] = Ar * zr - Ai * zi + Br * arq + Bi * aiq;
        ui[pb] = Ar * zi + Ai * zr + Bi * arq - Br * aiq;
      }
    }
  }
  __builtin_amdgcn_sched_barrier(0);

  // ---- inverse: in-lane DIT-16, inv mid-twiddle, cross-lane DIT-64 ----
  #pragma unroll
  for (int s = 0; s < 4; ++s) {
    const int hh = 1 << s;
    #pragma unroll
    for (int i = 0; i < 16; ++i) if (!(i & hh)) {
      const int tw = (i & (hh - 1)) * (16 / hh);
      float tr2 = ur[i + hh] * CW16[tw] - ui[i + hh] * SW16[tw];
      float ti2 = ui[i + hh] * CW16[tw] + ur[i + hh] * SW16[tw];
      ur[i + hh] = ur[i] - tr2; ui[i + hh] = ui[i] - ti2;
      ur[i] += tr2; ui[i] += ti2;
    }
  }
  #pragma unroll
  for (int j = 1; j < 16; ++j) {
    const float rev = (float)(j * kap) * (1.0f / 1024.0f);
    const float sn = hsin(rev), cs = hcos(rev);
    float t = ur[j] * cs - ui[j] * sn;
    ui[j] = ui[j] * cs + ur[j] * sn;
    ur[j] = t;
  }
  #pragma unroll
  for (int s = 0; s < 6; ++s) {
    const int hh = 1 << s;
    const int j = lane & (hh - 1);
    const float rev = (float)j * (0.5f / (float)hh);
    const bool hi = (lane & hh) != 0;
    const float c  = hi ? hcos(rev) : 1.0f;
    const float sv = hi ? hsin(rev) : 0.0f;
    const float sgn = hi ? -1.0f : 1.0f;
    #pragma unroll
    for (int r = 0; r < 16; ++r) {
      float vr = fmaf(-ui[r], sv, ur[r] * c);
      float vi = fmaf(ur[r], sv, ui[r] * c);
      float pvr = __shfl_xor(vr, hh, 64);
      float pvi = __shfl_xor(vi, hh, 64);
      ur[r] = fmaf(sgn, vr, pvr);
      ui[r] = fmaf(sgn, vi, pvi);
    }
  }

  // ---- store: u32 j = (y[32*lane+2j], y[32*lane+2j+1]); 64B contiguous/lane ----
  uint4* dst = (uint4*)(yT + col * 2048) + lane * 4;
  #pragma unroll
  for (int g = 0; g < 4; ++g) {
    uint4 o;
    o.x = pack2bf(ur[4 * g + 0], ui[4 * g + 0]);
    o.y = pack2bf(ur[4 * g + 1], ui[4 * g + 1]);
    o.z = pack2bf(ur[4 * g + 2], ui[4 * g + 2]);
    o.w = pack2bf(ur[4 * g + 3], ui[4 * g + 3]);
    dst[g] = o;
  }
}

// ---------- fallback (R3-proven): FFT-2048 reading x directly via LDS staging ----------
__global__ __attribute__((amdgpu_flat_work_group_size(512, 512)))
__attribute__((amdgpu_waves_per_eu(2, 4)))
void fft_gate_k(const float* __restrict__ x,
                const unsigned int* __restrict__ gt,
                unsigned short* __restrict__ y) {
  __shared__ float lds[8 * 516];
  const int tid = threadIdx.x;
  const int w = tid >> 6;
  const int lane = tid & 63;
  const int bid = blockIdx.x;
  const int swz = (bid & 7) * 256 + (bid >> 3);
  const int h0 = (swz & 255) << 3;
  const int b = swz >> 8;
  const int hh = tid & 7, srow = tid >> 3;

  float ur[32], ui[32];
  const size_t xbase = ((size_t)b * 2048) * 2048 + h0;

  for (int c = 0; c < 4; ++c) {
    #pragma unroll
    for (int q = 0; q < 8; ++q) {
      int soff = q * 64 + srow;
      float v = x[xbase + (size_t)(c * 512 + soff) * 2048 + hh];
      lds[hh * 516 + (soff ^ ((soff >> 5) & 15))] = v;
    }
    __syncthreads();
    if ((lane >> 4) == c) {
      const int li = lane & 15;
      #pragma unroll
      for (int j = 0; j < 32; ++j) {
        ur[j] = lds[w * 516 + ((32 * li + j) ^ li)];
        ui[j] = 0.f;
      }
    }
    __syncthreads();
  }

  fwd_core(ur, ui, lane);
  {
    const int kap = bitrev6(lane);
    const unsigned int* grow = gt + (size_t)(h0 + w) * 2048;
    #pragma unroll
    for (int p = 0; p < 32; ++p) {
      unsigned int g = grow[(BR5[p] << 6) + kap];
      float gre = bflo(g), gim = bfhi(g);
      float t = ur[p] * gre - ui[p] * gim;
      ui[p] = ur[p] * gim + ui[p] * gre;
      ur[p] = t;
    }
  }
  inv_core(ur, ui, lane);

  for (int c = 0; c < 4; ++c) {
    if ((lane >> 4) == c) {
      const int li = lane & 15;
      #pragma unroll
      for (int r = 0; r < 32; ++r)
        lds[w * 516 + ((32 * li + r) ^ li)] = ur[r];
    }
    __syncthreads();
    #pragma unroll
    for (int q = 0; q < 8; ++q) {
      int soff = q * 64 + srow;
      float v = lds[hh * 516 + (soff ^ ((soff >> 5) & 15))];
      y[xbase + (size_t)(c * 512 + soff) * 2048 + hh] = f2bf(v);
    }
    __syncthreads();
  }
}

// ---------- GEMM fallback: m97-style 128x128 tile ----------
__global__ __launch_bounds__(256) void gemm_k(const unsigned short* __restrict__ A,
                                              const unsigned short* __restrict__ Bw,
                                              const float* __restrict__ bias,
                                              float* __restrict__ C) {
  __shared__ unsigned short sA[128 * 32];
  __shared__ unsigned short sB[128 * 32];
  const int tid = threadIdx.x;
  const int nwg = gridDim.x;
  const int cpx = nwg >> 3;
  const int bid = blockIdx.x;
  const int swz = (bid & 7) * cpx + (bid >> 3);
  const int bm = swz >> 4, bn = swz & 15;
  const int m0 = bm << 7, n0 = bn << 7;
  const int w = tid >> 6, lane = tid & 63;
  const int arow = tid >> 2, koff = (tid & 3) << 3;
  const unsigned short* gA = A + (size_t)(m0 + arow) * 2048 + koff;
  const unsigned short* gB = Bw + (size_t)(n0 + arow) * 2048 + koff;
  char* sAb = (char*)sA + w * 1024;
  char* sBb = (char*)sB + w * 1024;

  f32x4 acc[4][4];
  #pragma unroll
  for (int i = 0; i < 4; ++i)
    #pragma unroll
    for (int j = 0; j < 4; ++j) acc[i][j] = (f32x4){0.f, 0.f, 0.f, 0.f};

  const int wr = w >> 1, wc = w & 1;
  const int row16 = lane & 15, kb = lane >> 4;

  for (int k0 = 0; k0 < 2048; k0 += 32) {
    glds16(gA + k0, sAb);
    glds16(gA + 64 * 2048 + k0, sAb + 4096);
    glds16(gB + k0, sBb);
    glds16(gB + 64 * 2048 + k0, sBb + 4096);
    __syncthreads();
    bf16x8 af[4], bfr[4];
    #pragma unroll
    for (int i = 0; i < 4; ++i) {
      int r = (wr << 6) + (i << 4) + row16;
      af[i] = *(const bf16x8*)(sA + r * 32 + (kb << 3));
    }
    #pragma unroll
    for (int j2 = 0; j2 < 4; ++j2) {
      int r = (wc << 6) + (j2 << 4) + row16;
      bfr[j2] = *(const bf16x8*)(sB + r * 32 + (kb << 3));
    }
    #pragma unroll
    for (int i = 0; i < 4; ++i)
      #pragma unroll
      for (int j2 = 0; j2 < 4; ++j2)
        acc[i][j2] = __builtin_amdgcn_mfma_f32_16x16x32_bf16(af[i], bfr[j2], acc[i][j2], 0, 0, 0);
    __syncthreads();
  }

  const int rq = lane >> 4;
  #pragma unroll
  for (int j2 = 0; j2 < 4; ++j2) {
    int oc = n0 + (wc << 6) + (j2 << 4) + row16;
    float bj = bias[oc];
    #pragma unroll
    for (int i = 0; i < 4; ++i) {
      int mr = m0 + (wr << 6) + (i << 4) + (rq << 2);
      #pragma unroll
      for (int q = 0; q < 4; ++q)
        C[(size_t)(mr + q) * 2048 + oc] = acc[i][j2][q] + bj;
    }
  }
}

// ---------- GEMM main: 256x256 tile, 4-stage pipeline, 2-phase K-step + setprio ----------
// (R13-verified: 142 µs, MfmaUtil 41.7%. Frozen this round.)
__global__ __launch_bounds__(512) void gemm8_k(const unsigned short* __restrict__ A,
                                               const unsigned short* __restrict__ Bw,
                                               const float* __restrict__ bias,
                                               float* __restrict__ C) {
  extern __shared__ char lds[];   // 4 x (A 16KB + B 16KB) = 128 KiB
  const int tid = threadIdx.x;
  const int w = tid >> 6, lane = tid & 63;
  const int bid = blockIdx.x;
  const int swz = (bid & 7) * 64 + (bid >> 3);   // 512 wgs, 8 XCDs, bijective
  const int m0 = (swz >> 3) << 8;
  const int n0 = (swz & 7) << 8;
  const int wr = w >> 2, wc = w & 3;
  const int row16 = lane & 15, kb = lane >> 4;

  const int lr = lane >> 2, ls = lane & 3;
  const int r0 = (w << 5) + lr, r1 = r0 + 16;
  const unsigned short* pA0 = A  + (size_t)(m0 + r0) * 2048 + ((ls ^ ((r0 >> 1) & 3)) << 3);
  const unsigned short* pA1 = A  + (size_t)(m0 + r1) * 2048 + ((ls ^ ((r1 >> 1) & 3)) << 3);
  const unsigned short* pB0 = Bw + (size_t)(n0 + r0) * 2048 + ((ls ^ ((r0 >> 1) & 3)) << 3);
  const unsigned short* pB1 = Bw + (size_t)(n0 + r1) * 2048 + ((ls ^ ((r1 >> 1) & 3)) << 3);
  const int dW = w << 11;

  f32x4 acc[8][4];
  #pragma unroll
  for (int i = 0; i < 8; ++i)
    #pragma unroll
    for (int j = 0; j < 4; ++j) acc[i][j] = (f32x4){0.f, 0.f, 0.f, 0.f};

  auto STAGE_A = [&](int t) {
    char* base = lds + ((t & 3) << 15);
    const int k0 = t << 5;
    glds16(pA0 + k0, base + dW);
    glds16(pA1 + k0, base + dW + 1024);
  };
  auto STAGE_B = [&](int t) {
    char* base = lds + ((t & 3) << 15);
    const int k0 = t << 5;
    glds16(pB0 + k0, base + 16384 + dW);
    glds16(pB1 + k0, base + 16384 + dW + 1024);
  };
  auto LDA4 = [&](const char* base, int i0, bf16x8 (&af)[4]) {
    #pragma unroll
    for (int i = 0; i < 4; ++i) {
      const int r = (wr << 7) + ((i0 + i) << 4) + row16;
      af[i] = *(const bf16x8*)(base + (r << 6) + ((kb ^ ((r >> 1) & 3)) << 4));
    }
  };
  auto LDB4 = [&](const char* base, bf16x8 (&bfr)[4]) {
    #pragma unroll
    for (int j = 0; j < 4; ++j) {
      const int r = (wc << 6) + (j << 4) + row16;
      bfr[j] = *(const bf16x8*)(base + 16384 + (r << 6) + ((kb ^ ((r >> 1) & 3)) << 4));
    }
  };
  auto MM16 = [&](const bf16x8 (&af)[4], const bf16x8 (&bfr)[4], int i0) {
    #pragma unroll
    for (int i = 0; i < 4; ++i)
      #pragma unroll
      for (int j = 0; j < 4; ++j)
        acc[i0 + i][j] = __builtin_amdgcn_mfma_f32_16x16x32_bf16(af[i], bfr[j], acc[i0 + i][j], 0, 0, 0);
  };
  auto COMPUTE = [&](int t) {   // monolithic form, used for the tail only
    const char* base = lds + ((t & 3) << 15);
    bf16x8 af[4], af2[4], bfr[4];
    LDA4(base, 0, af); LDA4(base, 4, af2); LDB4(base, bfr);
    MM16(af, bfr, 0); MM16(af2, bfr, 4);
  };

  // prologue: stage tiles 0..2 (both halves); wait tile 0
  STAGE_A(0); STAGE_B(0); STAGE_A(1); STAGE_B(1); STAGE_A(2); STAGE_B(2);
  asm volatile("s_waitcnt vmcnt(8)" ::: "memory");
  __builtin_amdgcn_s_barrier();
  __builtin_amdgcn_sched_barrier(0);

  for (int t = 0; t < 61; ++t) {
    const char* base = lds + ((t & 3) << 15);
    // ---- phase 1: A-rows 0..3 x all B; issue A-half of t+3 ----
    bf16x8 af[4], bfr[4];
    LDA4(base, 0, af);
    LDB4(base, bfr);
    STAGE_A(t + 3);
    asm volatile("s_waitcnt lgkmcnt(0)" ::: "memory");
    __builtin_amdgcn_sched_barrier(0);      // rule #18: pin MFMA after lgkmcnt
    __builtin_amdgcn_s_setprio(1);
    MM16(af, bfr, 0);
    __builtin_amdgcn_s_setprio(0);
    __builtin_amdgcn_s_barrier();
    // ---- phase 2: A-rows 4..7 x all B; issue B-half of t+3 ----
    bf16x8 af2[4];
    LDA4(base, 4, af2);
    STAGE_B(t + 3);
    asm volatile("s_waitcnt lgkmcnt(0)" ::: "memory");
    __builtin_amdgcn_sched_barrier(0);
    __builtin_amdgcn_s_setprio(1);
    MM16(af2, bfr, 4);
    __builtin_amdgcn_s_setprio(0);
    asm volatile("s_waitcnt vmcnt(8)" ::: "memory");   // tile t+1 landed
    __builtin_amdgcn_s_barrier();
    __builtin_amdgcn_sched_barrier(0);
  }
  COMPUTE(61);
  asm volatile("s_waitcnt vmcnt(4)" ::: "memory");
  __builtin_amdgcn_s_barrier();
  __builtin_amdgcn_sched_barrier(0);
  COMPUTE(62);
  asm volatile("s_waitcnt vmcnt(0)" ::: "memory");
  __builtin_amdgcn_s_barrier();
  __builtin_amdgcn_sched_barrier(0);
  COMPUTE(63);

  const int rq = lane >> 4;
  #pragma unroll
  for (int j = 0; j < 4; ++j) {
    const int oc = n0 + (wc << 6) + (j << 4) + row16;
    const float bj = bias[oc];
    #pragma unroll
    for (int i = 0; i < 8; ++i) {
      const int mr = m0 + (wr << 7) + (i << 4) + (rq << 2);
      #pragma unroll
      for (int q = 0; q < 4; ++q)
        C[(size_t)(mr + q) * 2048 + oc] = acc[i][j][q] + bj;
    }
  }
}

extern "C" void kernel_launch(void* const* d_in, const int* in_sizes, int n_in,
                              void* d_out, int out_size, void* d_ws, size_t ws_size,
                              hipStream_t stream) {
  const float* x  = (const float*)d_in[0];
  const float* gr = (const float*)d_in[1];
  const float* gi = (const float*)d_in[2];
  const float* W  = (const float*)d_in[3];
  const float* bs = (const float*)d_in[4];
  float* out = (float*)d_out;

  char* ws = (char*)d_ws;
  unsigned short* yb = (unsigned short*)ws;                          // 64 MB  y bf16 [b,s,h]
  unsigned short* Wb = (unsigned short*)(ws + (64ull << 20));        // 8 MB   W bf16
  unsigned int*   gt = (unsigned int*)(ws + (72ull << 20));          // 16 MB  gate (fallback)
  uint2*          ab = (uint2*)(ws + (72ull << 20));                 // 16 MB  A/B table (fast)
  float*          xT = (float*)(ws + (88ull << 20));                 // 128 MB x transposed [b,h,s]
  unsigned short* yT = (unsigned short*)(ws + (216ull << 20));       // 64 MB  y transposed [b,h,s]
  const bool fast = ws_size >= (280ull << 20);

  hipLaunchKernelGGL(wconv_k, dim3(4096), dim3(256), 0, stream, W, Wb);
  if (fast) {
    hipLaunchKernelGGL(gate_ab_k, dim3(32, 64), dim3(256), 0, stream, gr, gi, ab);
    hipLaunchKernelGGL(xtrans_k, dim3(64, 64, 8), dim3(256), 0, stream, x, xT);
    hipLaunchKernelGGL(fftr_k, dim3(4096), dim3(256), 0, stream, xT, ab, yT);
    hipLaunchKernelGGL(ytrans_k, dim3(32, 32, 8), dim3(256), 0, stream, yT, yb);
  } else {
    hipLaunchKernelGGL(gate_pack_k, dim3(64, 64), dim3(256), 0, stream, gr, gi, gt);
    hipLaunchKernelGGL(fft_gate_k, dim3(2048), dim3(512), 0, stream, x, gt, yb);
  }

  const bool big = hipFuncSetAttribute((const void*)gemm8_k,
                                       hipFuncAttributeMaxDynamicSharedMemorySize,
                                       131072) == hipSuccess;
  if (big) {
    hipLaunchKernelGGL(gemm8_k, dim3(512), dim3(512), 131072, stream, yb, Wb, bs, out);
  } else {
    hipLaunchKernelGGL(gemm_k, dim3(2048), dim3(256), 0, stream, yb, Wb, bs, out);
  }
}

// Round 16
// 338.037 us; speedup vs baseline: 1.5898x; 1.0358x over previous
//
#include <hip/hip_runtime.h>
#include <math.h>

typedef __attribute__((ext_vector_type(8))) short bf16x8;
typedef __attribute__((ext_vector_type(4))) float f32x4;

__device__ __forceinline__ unsigned short f2bf(float f) {
  unsigned int u = __float_as_uint(f);
  unsigned int r = (u + 0x7fffu + ((u >> 16) & 1u)) >> 16;
  return (unsigned short)r;
}
__device__ __forceinline__ unsigned int pack2bf(float a, float b) {
  return (unsigned int)f2bf(a) | ((unsigned int)f2bf(b) << 16);
}
__device__ __forceinline__ float bflo(unsigned int g) { return __uint_as_float(g << 16); }
__device__ __forceinline__ float bfhi(unsigned int g) { return __uint_as_float(g & 0xffff0000u); }

__device__ __forceinline__ void glds16(const void* gp, void* lp) {
  __builtin_amdgcn_global_load_lds(
      (const __attribute__((address_space(1))) void*)gp,
      (__attribute__((address_space(3))) void*)lp, 16, 0, 0);
}

// cos/sin(pi*j/16), j=0..15 — cover all in-lane FFT16/FFT32 twiddles
__device__ __constant__ float CW16[16] = {
  1.0f, 0.9807852804032304f, 0.9238795325112867f, 0.8314696123025452f,
  0.7071067811865476f, 0.5555702330196022f, 0.3826834323650898f, 0.19509032201612828f,
  0.0f, -0.19509032201612828f, -0.3826834323650898f, -0.5555702330196022f,
  -0.7071067811865476f, -0.8314696123025452f, -0.9238795325112867f, -0.9807852804032304f};
__device__ __constant__ float SW16[16] = {
  0.0f, 0.19509032201612828f, 0.3826834323650898f, 0.5555702330196022f,
  0.7071067811865476f, 0.8314696123025452f, 0.9238795325112867f, 0.9807852804032304f,
  1.0f, 0.9807852804032304f, 0.9238795325112867f, 0.8314696123025452f,
  0.7071067811865476f, 0.5555702330196022f, 0.3826834323650898f, 0.19509032201612828f};
__device__ __constant__ int BR5[32] = {
  0,16,8,24,4,20,12,28,2,18,10,26,6,22,14,30,
  1,17,9,25,5,21,13,29,3,19,11,27,7,23,15,31};

__device__ __forceinline__ int bitrev6(int l) {
  return ((l&1)<<5)|((l&2)<<3)|((l&4)<<1)|((l&8)>>1)|((l&16)>>3)|((l&32)>>5);
}

// hardware sin/cos: input in REVOLUTIONS (angle/2pi); all our args are in [0,1)
__device__ __forceinline__ float hsin(float rev) { return __builtin_amdgcn_sinf(rev); }
__device__ __forceinline__ float hcos(float rev) { return __builtin_amdgcn_cosf(rev); }

// ================= 2048-point cores (fallback path only) =================
__device__ __forceinline__ void fwd_core(float (&ur)[32], float (&ui)[32], const int lane) {
  #pragma unroll
  for (int s = 0; s < 6; ++s) {
    const int h = 32 >> s;
    const int j = lane & (h - 1);
    const float rev = (float)j * (0.5f / (float)h);
    const bool hi = (lane & h) != 0;
    const float c  = hi ? hcos(rev) : 1.0f;
    const float sv = hi ? hsin(rev) : 0.0f;
    const float sgn = hi ? -1.0f : 1.0f;
    #pragma unroll
    for (int r = 0; r < 32; ++r) {
      float pr = __shfl_xor(ur[r], h, 64);
      float pi = __shfl_xor(ui[r], h, 64);
      float tr = fmaf(sgn, ur[r], pr);
      float ti = fmaf(sgn, ui[r], pi);
      ur[r] = fmaf(ti, sv, tr * c);
      ui[r] = fmaf(-tr, sv, ti * c);
    }
  }
  const int kap = bitrev6(lane);
  #pragma unroll
  for (int j = 1; j < 32; ++j) {
    const float rev = (float)(j * kap) * (1.0f / 2048.0f);
    const float sn = hsin(rev), cs = hcos(rev);
    float t = ur[j] * cs + ui[j] * sn;
    ui[j] = ui[j] * cs - ur[j] * sn;
    ur[j] = t;
  }
  #pragma unroll
  for (int s = 0; s < 5; ++s) {
    const int h = 16 >> s;
    #pragma unroll
    for (int i = 0; i < 32; ++i) if (!(i & h)) {
      const int tw = (i & (h - 1)) * (16 / h);
      float dr = ur[i] - ur[i + h], di = ui[i] - ui[i + h];
      ur[i] += ur[i + h]; ui[i] += ui[i + h];
      ur[i + h] = dr * CW16[tw] + di * SW16[tw];
      ui[i + h] = di * CW16[tw] - dr * SW16[tw];
    }
  }
}

__device__ __forceinline__ void inv_core(float (&ur)[32], float (&ui)[32], const int lane) {
  const int kap = bitrev6(lane);
  #pragma unroll
  for (int s = 0; s < 5; ++s) {
    const int h = 1 << s;
    #pragma unroll
    for (int i = 0; i < 32; ++i) if (!(i & h)) {
      const int tw = (i & (h - 1)) * (16 / h);
      float tr2 = ur[i + h] * CW16[tw] - ui[i + h] * SW16[tw];
      float ti2 = ui[i + h] * CW16[tw] + ur[i + h] * SW16[tw];
      ur[i + h] = ur[i] - tr2; ui[i + h] = ui[i] - ti2;
      ur[i] += tr2; ui[i] += ti2;
    }
  }
  #pragma unroll
  for (int j = 1; j < 32; ++j) {
    const float rev = (float)(j * kap) * (1.0f / 2048.0f);
    const float sn = hsin(rev), cs = hcos(rev);
    float t = ur[j] * cs - ui[j] * sn;
    ui[j] = ui[j] * cs + ur[j] * sn;
    ur[j] = t;
  }
  #pragma unroll
  for (int s = 0; s < 6; ++s) {
    const int h = 1 << s;
    const int j = lane & (h - 1);
    const float rev = (float)j * (0.5f / (float)h);
    const bool hi = (lane & h) != 0;
    const float c  = hi ? hcos(rev) : 1.0f;
    const float sv = hi ? hsin(rev) : 0.0f;
    const float sgn = hi ? -1.0f : 1.0f;
    #pragma unroll
    for (int r = 0; r < 32; ++r) {
      float vr = fmaf(-ui[r], sv, ur[r] * c);
      float vi = fmaf(ur[r], sv, ui[r] * c);
      float pvr = __shfl_xor(vr, h, 64);
      float pvi = __shfl_xor(vi, h, 64);
      ur[r] = fmaf(sgn, vr, pvr);
      ui[r] = fmaf(sgn, vi, pvi);
    }
  }
}

// ---------- gate transpose + Hermitian extend + pack (fallback path) ----------
__global__ __launch_bounds__(256) void gate_pack_k(const float* __restrict__ gr,
                                                   const float* __restrict__ gi,
                                                   unsigned int* __restrict__ gt) {
  __shared__ float tr[32][33];
  __shared__ float ti[32][33];
  const int t = threadIdx.x;
  const int k0 = blockIdx.x * 32, hb = blockIdx.y * 32;
  const int hx = t & 31, fr = t >> 5;
  #pragma unroll
  for (int p = 0; p < 4; ++p) {
    int ff = p * 8 + fr;
    int k = k0 + ff;
    int f = (k <= 1024) ? k : (2048 - k);
    float sg = (k <= 1024) ? 1.f : -1.f;
    tr[ff][hx] = gr[(size_t)f * 2048 + hb + hx] * (1.f / 2048.f);
    ti[ff][hx] = sg * gi[(size_t)f * 2048 + hb + hx] * (1.f / 2048.f);
  }
  __syncthreads();
  const int kk = t & 31, hr = t >> 5;
  #pragma unroll
  for (int p = 0; p < 4; ++p) {
    int hl = p * 8 + hr;
    float re = tr[kk][hl], im = ti[kk][hl];
    gt[(size_t)(hb + hl) * 2048 + k0 + kk] =
        (unsigned int)f2bf(re) | ((unsigned int)f2bf(im) << 16);
  }
}

// ---------- A/B table for the rfft path (R12-verified) ----------
__global__ __launch_bounds__(256) void gate_ab_k(const float* __restrict__ gr,
                                                 const float* __restrict__ gi,
                                                 uint2* __restrict__ ab) {
  __shared__ unsigned int uA[32][33];
  __shared__ unsigned int uB[32][33];
  const int t = threadIdx.x;
  const int k0 = blockIdx.x * 32, h0 = blockIdx.y * 32;
  const int c = t & 31, r = t >> 5;
  #pragma unroll
  for (int pp = 0; pp < 4; ++pp) {
    const int kk = pp * 8 + r;
    const int k = k0 + kk;
    const int h = h0 + c;
    const float gkr = gr[(size_t)k * 2048 + h];
    const float gki = gi[(size_t)k * 2048 + h];
    const float gcr = gr[(size_t)(1024 - k) * 2048 + h];
    const float gci = gi[(size_t)(1024 - k) * 2048 + h];
    const float inv = 1.0f / 1024.0f;
    float Ar, Ai, Br, Bi;
    if (k == 0) {
      Ar = (gkr + gcr) * 0.5f * inv; Ai = 0.f;
      Br = 0.f; Bi = (gkr - gcr) * 0.5f * inv;
    } else {
      const float rev = (float)k * (1.0f / 2048.0f);
      const float sn = hsin(rev), cs = hcos(rev);
      const float Sr = (gkr + gcr) * 0.5f, Si = (gki - gci) * 0.5f;
      const float Dr = (gkr - gcr) * 0.5f, Di = (gki + gci) * 0.5f;
      Ar = (Sr - sn * Dr) * inv; Ai = (Si - sn * Di) * inv;
      Br = (-cs * Di) * inv;     Bi = (cs * Dr) * inv;
    }
    uA[kk][c] = pack2bf(Ar, Ai);
    uB[kk][c] = pack2bf(Br, Bi);
  }
  __syncthreads();
  #pragma unroll
  for (int pp = 0; pp < 4; ++pp) {
    const int hh = pp * 8 + r;
    ab[(size_t)(h0 + hh) * 1024 + k0 + c] = make_uint2(uA[c][hh], uB[c][hh]);
  }
}

// ---------- W f32 -> bf16 ----------
__global__ __launch_bounds__(256) void wconv_k(const float* __restrict__ W,
                                               unsigned short* __restrict__ Wb) {
  int i = blockIdx.x * 256 + threadIdx.x;
  float4 v = ((const float4*)W)[i];
  ushort4 o;
  o.x = f2bf(v.x); o.y = f2bf(v.y); o.z = f2bf(v.z); o.w = f2bf(v.w);
  ((ushort4*)Wb)[i] = o;
}

// ---------- T1: x [b,s,h] f32 -> xT [b,h,s] BF16, 64x64 tiles ----------
// bf16 output halves xtrans write traffic AND fftr read traffic. 64x64 tile
// keeps both sides >=128B coalesced (f32 reads 256B/row, bf16 writes 128B/row).
// LDS [64][65]: write phase row-contiguous; read phase banks (8j+e+h)%32 ->
// 2 lanes/bank = free (m136).
__global__ __launch_bounds__(256) void xtrans_k(const float* __restrict__ x,
                                                unsigned short* __restrict__ xT) {
  __shared__ float t[64][65];
  const int b = blockIdx.z;
  const int s0 = blockIdx.x * 64, h0 = blockIdx.y * 64;
  const float* xb = x + ((size_t)b * 2048) * 2048;
  unsigned short* xTb = xT + ((size_t)b * 2048) * 2048;
  const int c4 = (threadIdx.x & 15) * 4;
  const int r0 = threadIdx.x >> 4;     // 0..15
  #pragma unroll
  for (int p = 0; p < 4; ++p) {
    const int rr = p * 16 + r0;
    float4 v = *(const float4*)(xb + (size_t)(s0 + rr) * 2048 + h0 + c4);
    t[rr][c4 + 0] = v.x; t[rr][c4 + 1] = v.y;
    t[rr][c4 + 2] = v.z; t[rr][c4 + 3] = v.w;
  }
  __syncthreads();
  const int j = threadIdx.x & 7;       // 8 lanes per h-row (64 s * 2B = 128B)
  const int hr0 = threadIdx.x >> 3;    // 0..31
  #pragma unroll
  for (int p = 0; p < 2; ++p) {
    const int hh = p * 32 + hr0;
    uint4 o;
    o.x = pack2bf(t[j * 8 + 0][hh], t[j * 8 + 1][hh]);
    o.y = pack2bf(t[j * 8 + 2][hh], t[j * 8 + 3][hh]);
    o.z = pack2bf(t[j * 8 + 4][hh], t[j * 8 + 5][hh]);
    o.w = pack2bf(t[j * 8 + 6][hh], t[j * 8 + 7][hh]);
    *(uint4*)(xTb + (size_t)(h0 + hh) * 2048 + s0 + j * 8) = o;
  }
}

// ---------- T2: yT [b,h,s] -> y [b,s,h], bf16 64x64 tiles ----------
__global__ __launch_bounds__(256) void ytrans_k(const unsigned short* __restrict__ yT,
                                                unsigned short* __restrict__ y) {
  __shared__ unsigned short t[64][66];
  const int b = blockIdx.z;
  const int h0 = blockIdx.x * 64, s0 = blockIdx.y * 64;
  const unsigned short* src = yT + ((size_t)b * 2048 + h0) * 2048 + s0;
  unsigned short* dst = y + ((size_t)b * 2048 + s0) * 2048 + h0;
  const int c = threadIdx.x & 15, r = threadIdx.x >> 4;
  #pragma unroll
  for (int p = 0; p < 4; ++p) {
    int rr = p * 16 + r;
    ushort4 v = *(const ushort4*)(src + (size_t)rr * 2048 + c * 4);
    *(ushort4*)&t[rr][c * 4] = v;
  }
  __syncthreads();
  #pragma unroll
  for (int p = 0; p < 4; ++p) {
    int rr = p * 16 + r;
    ushort4 o;
    o.x = t[c * 4 + 0][rr]; o.y = t[c * 4 + 1][rr];
    o.z = t[c * 4 + 2][rr]; o.w = t[c * 4 + 3][rr];
    *(ushort4*)(dst + (size_t)rr * 2048 + c * 4) = o;
  }
}

// ---------- rfft FFT: one wave per column; z[n]=x[2n]+i*x[2n+1], FFT-1024 ----------
// R15: (1) reads BF16 xT (64B/lane, half the traffic); (2) ab table staged
// into LDS via 8 coalesced glds16/wave (frees the 32 VGPRs R14 held across the
// whole forward FFT; gate reads become 2-way-bank ds_read_b64).
__global__ __attribute__((amdgpu_flat_work_group_size(256, 256)))
__attribute__((amdgpu_waves_per_eu(2, 4)))
void fftr_k(const unsigned short* __restrict__ xT,
            const uint2* __restrict__ ab,
            unsigned short* __restrict__ yT) {
  __shared__ float snap[4][32];
  __shared__ uint2 labs[4][1024];      // per-wave copy of ab row (8KB)
  const int tid = threadIdx.x;
  const int w = tid >> 6, lane = tid & 63;
  const size_t col = (size_t)blockIdx.x * 4 + w;   // b*2048 + h
  const int h = (int)(col & 2047);
  const int kap = bitrev6(lane);
  constexpr int BR4[16]   = {0,8,4,12,2,10,6,14,1,9,5,13,3,11,7,15};
  constexpr int P0L16[16] = {0,1,3,2,7,6,5,4,15,14,13,12,11,10,9,8};

  // ---- stage ab row into LDS (coalesced; hides under fwd FFT) ----
  {
    const char* gsrc = (const char*)(ab + (size_t)h * 1024);
    char* ldst = (char*)&labs[w][0];
    #pragma unroll
    for (int p8 = 0; p8 < 8; ++p8)
      glds16(gsrc + p8 * 1024 + lane * 16, ldst + p8 * 1024);
  }

  // ---- load x column (bf16, 64B per lane) and unpack ----
  float ur[16], ui[16];
  {
    const unsigned short* xc = xT + col * 2048;
    #pragma unroll
    for (int q = 0; q < 4; ++q) {
      uint4 v = *(const uint4*)(xc + lane * 32 + q * 8);
      ur[4 * q + 0] = bflo(v.x); ui[4 * q + 0] = bfhi(v.x);
      ur[4 * q + 1] = bflo(v.y); ui[4 * q + 1] = bfhi(v.y);
      ur[4 * q + 2] = bflo(v.z); ui[4 * q + 2] = bfhi(v.z);
      ur[4 * q + 3] = bflo(v.w); ui[4 * q + 3] = bfhi(v.w);
    }
  }

  // ---- forward cross-lane DIF-64 (branchless) ----
  #pragma unroll
  for (int s = 0; s < 6; ++s) {
    const int hh = 32 >> s;
    const int j = lane & (hh - 1);
    const float rev = (float)j * (0.5f / (float)hh);
    const bool hi = (lane & hh) != 0;
    const float c  = hi ? hcos(rev) : 1.0f;
    const float sv = hi ? hsin(rev) : 0.0f;
    const float sgn = hi ? -1.0f : 1.0f;
    #pragma unroll
    for (int r = 0; r < 16; ++r) {
      float pr = __shfl_xor(ur[r], hh, 64);
      float pi = __shfl_xor(ui[r], hh, 64);
      float tr = fmaf(sgn, ur[r], pr);
      float ti = fmaf(sgn, ui[r], pi);
      ur[r] = fmaf(ti, sv, tr * c);
      ui[r] = fmaf(-tr, sv, ti * c);
    }
  }
  // ---- forward mid-twiddle e^{-2pi i j kap/1024} ----
  #pragma unroll
  for (int j = 1; j < 16; ++j) {
    const float rev = (float)(j * kap) * (1.0f / 1024.0f);
    const float sn = hsin(rev), cs = hcos(rev);
    float t = ur[j] * cs + ui[j] * sn;
    ui[j] = ui[j] * cs - ur[j] * sn;
    ur[j] = t;
  }
  // ---- in-lane DIF-16 ----
  #pragma unroll
  for (int s = 0; s < 4; ++s) {
    const int hh = 8 >> s;
    #pragma unroll
    for (int i = 0; i < 16; ++i) if (!(i & hh)) {
      const int tw = (i & (hh - 1)) * (16 / hh);
      float dr = ur[i] - ur[i + hh], di = ui[i] - ui[i + hh];
      ur[i] += ur[i + hh]; ui[i] += ui[i + hh];
      ur[i + hh] = dr * CW16[tw] + di * SW16[tw];
      ui[i + hh] = di * CW16[tw] - dr * SW16[tw];
    }
  }

  // ---- gate: Z'[k] = A Z[k] + B conj(Z[1024-k]) ----
  if (lane == 0) {
    #pragma unroll
    for (int p = 0; p < 16; ++p) { snap[w][2 * p] = ur[p]; snap[w][2 * p + 1] = ui[p]; }
  }
  asm volatile("s_waitcnt vmcnt(0)" ::: "memory");   // labs staged (wave-local)
  const int lsrc = bitrev6((64 - kap) & 63);
  const bool l0 = (lane == 0);
  #pragma unroll
  for (int c2 = 0; c2 < 4; ++c2) {
    __builtin_amdgcn_sched_barrier(0);   // cap shfl/snap hoisting to one chunk
    #pragma unroll
    for (int pp = 0; pp < 2; ++pp) {
      const int p = c2 * 2 + pp;
      const int pb = 15 - p;
      float arp = __shfl(ur[pb], lsrc), aip = __shfl(ui[pb], lsrc);  // partner of reg p
      float arq = __shfl(ur[p], lsrc),  aiq = __shfl(ui[p], lsrc);   // partner of reg pb
      float s0r = snap[w][2 * P0L16[p]],  s0i = snap[w][2 * P0L16[p] + 1];
      float s1r = snap[w][2 * P0L16[pb]], s1i = snap[w][2 * P0L16[pb] + 1];
      arp = l0 ? s0r : arp;  aip = l0 ? s0i : aip;
      arq = l0 ? s1r : arq;  aiq = l0 ? s1i : aiq;
      uint2 gp = labs[w][(BR4[p]  << 6) + kap];
      uint2 gq = labs[w][(BR4[pb] << 6) + kap];
      {
        float Ar = bflo(gp.x), Ai = bfhi(gp.x), Br = bflo(gp.y), Bi = bfhi(gp.y);
        float zr = ur[p], zi = ui[p];
        ur[p] = Ar * zr - Ai * zi + Br * arp + Bi * aip;
        ui[p] = Ar * zi + Ai * zr + Bi * arp - Br * aip;
      }
      {
        float Ar = bflo(gq.x), Ai = bfhi(gq.x), Br = bflo(gq.y), Bi = bfhi(gq.y);
        float zr = ur[pb], zi = ui[pb];
        ur[pb] = Ar * zr - Ai * zi + Br * arq + Bi * aiq;
        ui[pb] = Ar * zi + Ai * zr + Bi * arq - Br * aiq;
      }
    }
  }
  __builtin_amdgcn_sched_barrier(0);

  // ---- inverse: in-lane DIT-16, inv mid-twiddle, cross-lane DIT-64 ----
  #pragma unroll
  for (int s = 0; s < 4; ++s) {
    const int hh = 1 << s;
    #pragma unroll
    for (int i = 0; i < 16; ++i) if (!(i & hh)) {
      const int tw = (i & (hh - 1)) * (16 / hh);
      float tr2 = ur[i + hh] * CW16[tw] - ui[i + hh] * SW16[tw];
      float ti2 = ui[i + hh] * CW16[tw] + ur[i + hh] * SW16[tw];
      ur[i + hh] = ur[i] - tr2; ui[i + hh] = ui[i] - ti2;
      ur[i] += tr2; ui[i] += ti2;
    }
  }
  #pragma unroll
  for (int j = 1; j < 16; ++j) {
    const float rev = (float)(j * kap) * (1.0f / 1024.0f);
    const float sn = hsin(rev), cs = hcos(rev);
    float t = ur[j] * cs - ui[j] * sn;
    ui[j] = ui[j] * cs + ur[j] * sn;
    ur[j] = t;
  }
  #pragma unroll
  for (int s = 0; s < 6; ++s) {
    const int hh = 1 << s;
    const int j = lane & (hh - 1);
    const float rev = (float)j * (0.5f / (float)hh);
    const bool hi = (lane & hh) != 0;
    const float c  = hi ? hcos(rev) : 1.0f;
    const float sv = hi ? hsin(rev) : 0.0f;
    const float sgn = hi ? -1.0f : 1.0f;
    #pragma unroll
    for (int r = 0; r < 16; ++r) {
      float vr = fmaf(-ui[r], sv, ur[r] * c);
      float vi = fmaf(ur[r], sv, ui[r] * c);
      float pvr = __shfl_xor(vr, hh, 64);
      float pvi = __shfl_xor(vi, hh, 64);
      ur[r] = fmaf(sgn, vr, pvr);
      ui[r] = fmaf(sgn, vi, pvi);
    }
  }

  // ---- store: u32 j = (y[32*lane+2j], y[32*lane+2j+1]); 64B contiguous/lane ----
  uint4* dst = (uint4*)(yT + col * 2048) + lane * 4;
  #pragma unroll
  for (int g = 0; g < 4; ++g) {
    uint4 o;
    o.x = pack2bf(ur[4 * g + 0], ui[4 * g + 0]);
    o.y = pack2bf(ur[4 * g + 1], ui[4 * g + 1]);
    o.z = pack2bf(ur[4 * g + 2], ui[4 * g + 2]);
    o.w = pack2bf(ur[4 * g + 3], ui[4 * g + 3]);
    dst[g] = o;
  }
}

// ---------- fallback (R3-proven): FFT-2048 reading x directly via LDS staging ----------
__global__ __attribute__((amdgpu_flat_work_group_size(512, 512)))
__attribute__((amdgpu_waves_per_eu(2, 4)))
void fft_gate_k(const float* __restrict__ x,
                const unsigned int* __restrict__ gt,
                unsigned short* __restrict__ y) {
  __shared__ float lds[8 * 516];
  const int tid = threadIdx.x;
  const int w = tid >> 6;
  const int lane = tid & 63;
  const int bid = blockIdx.x;
  const int swz = (bid & 7) * 256 + (bid >> 3);
  const int h0 = (swz & 255) << 3;
  const int b = swz >> 8;
  const int hh = tid & 7, srow = tid >> 3;

  float ur[32], ui[32];
  const size_t xbase = ((size_t)b * 2048) * 2048 + h0;

  for (int c = 0; c < 4; ++c) {
    #pragma unroll
    for (int q = 0; q < 8; ++q) {
      int soff = q * 64 + srow;
      float v = x[xbase + (size_t)(c * 512 + soff) * 2048 + hh];
      lds[hh * 516 + (soff ^ ((soff >> 5) & 15))] = v;
    }
    __syncthreads();
    if ((lane >> 4) == c) {
      const int li = lane & 15;
      #pragma unroll
      for (int j = 0; j < 32; ++j) {
        ur[j] = lds[w * 516 + ((32 * li + j) ^ li)];
        ui[j] = 0.f;
      }
    }
    __syncthreads();
  }

  fwd_core(ur, ui, lane);
  {
    const int kap = bitrev6(lane);
    const unsigned int* grow = gt + (size_t)(h0 + w) * 2048;
    #pragma unroll
    for (int p = 0; p < 32; ++p) {
      unsigned int g = grow[(BR5[p] << 6) + kap];
      float gre = bflo(g), gim = bfhi(g);
      float t = ur[p] * gre - ui[p] * gim;
      ui[p] = ur[p] * gim + ui[p] * gre;
      ur[p] = t;
    }
  }
  inv_core(ur, ui, lane);

  for (int c = 0; c < 4; ++c) {
    if ((lane >> 4) == c) {
      const int li = lane & 15;
      #pragma unroll
      for (int r = 0; r < 32; ++r)
        lds[w * 516 + ((32 * li + r) ^ li)] = ur[r];
    }
    __syncthreads();
    #pragma unroll
    for (int q = 0; q < 8; ++q) {
      int soff = q * 64 + srow;
      float v = lds[hh * 516 + (soff ^ ((soff >> 5) & 15))];
      y[xbase + (size_t)(c * 512 + soff) * 2048 + hh] = f2bf(v);
    }
    __syncthreads();
  }
}

// ---------- GEMM fallback: m97-style 128x128 tile ----------
__global__ __launch_bounds__(256) void gemm_k(const unsigned short* __restrict__ A,
                                              const unsigned short* __restrict__ Bw,
                                              const float* __restrict__ bias,
                                              float* __restrict__ C) {
  __shared__ unsigned short sA[128 * 32];
  __shared__ unsigned short sB[128 * 32];
  const int tid = threadIdx.x;
  const int nwg = gridDim.x;
  const int cpx = nwg >> 3;
  const int bid = blockIdx.x;
  const int swz = (bid & 7) * cpx + (bid >> 3);
  const int bm = swz >> 4, bn = swz & 15;
  const int m0 = bm << 7, n0 = bn << 7;
  const int w = tid >> 6, lane = tid & 63;
  const int arow = tid >> 2, koff = (tid & 3) << 3;
  const unsigned short* gA = A + (size_t)(m0 + arow) * 2048 + koff;
  const unsigned short* gB = Bw + (size_t)(n0 + arow) * 2048 + koff;
  char* sAb = (char*)sA + w * 1024;
  char* sBb = (char*)sB + w * 1024;

  f32x4 acc[4][4];
  #pragma unroll
  for (int i = 0; i < 4; ++i)
    #pragma unroll
    for (int j = 0; j < 4; ++j) acc[i][j] = (f32x4){0.f, 0.f, 0.f, 0.f};

  const int wr = w >> 1, wc = w & 1;
  const int row16 = lane & 15, kb = lane >> 4;

  for (int k0 = 0; k0 < 2048; k0 += 32) {
    glds16(gA + k0, sAb);
    glds16(gA + 64 * 2048 + k0, sAb + 4096);
    glds16(gB + k0, sBb);
    glds16(gB + 64 * 2048 + k0, sBb + 4096);
    __syncthreads();
    bf16x8 af[4], bfr[4];
    #pragma unroll
    for (int i = 0; i < 4; ++i) {
      int r = (wr << 6) + (i << 4) + row16;
      af[i] = *(const bf16x8*)(sA + r * 32 + (kb << 3));
    }
    #pragma unroll
    for (int j2 = 0; j2 < 4; ++j2) {
      int r = (wc << 6) + (j2 << 4) + row16;
      bfr[j2] = *(const bf16x8*)(sB + r * 32 + (kb << 3));
    }
    #pragma unroll
    for (int i = 0; i < 4; ++i)
      #pragma unroll
      for (int j2 = 0; j2 < 4; ++j2)
        acc[i][j2] = __builtin_amdgcn_mfma_f32_16x16x32_bf16(af[i], bfr[j2], acc[i][j2], 0, 0, 0);
    __syncthreads();
  }

  const int rq = lane >> 4;
  #pragma unroll
  for (int j2 = 0; j2 < 4; ++j2) {
    int oc = n0 + (wc << 6) + (j2 << 4) + row16;
    float bj = bias[oc];
    #pragma unroll
    for (int i = 0; i < 4; ++i) {
      int mr = m0 + (wr << 6) + (i << 4) + (rq << 2);
      #pragma unroll
      for (int q = 0; q < 4; ++q)
        C[(size_t)(mr + q) * 2048 + oc] = acc[i][j2][q] + bj;
    }
  }
}

// ---------- GEMM main: 256x256 tile, 4-stage pipeline, 2-phase K-step + setprio ----------
// (R13-verified: 142 µs, MfmaUtil 41.7%. Frozen.)
__global__ __launch_bounds__(512) void gemm8_k(const unsigned short* __restrict__ A,
                                               const unsigned short* __restrict__ Bw,
                                               const float* __restrict__ bias,
                                               float* __restrict__ C) {
  extern __shared__ char lds[];   // 4 x (A 16KB + B 16KB) = 128 KiB
  const int tid = threadIdx.x;
  const int w = tid >> 6, lane = tid & 63;
  const int bid = blockIdx.x;
  const int swz = (bid & 7) * 64 + (bid >> 3);   // 512 wgs, 8 XCDs, bijective
  const int m0 = (swz >> 3) << 8;
  const int n0 = (swz & 7) << 8;
  const int wr = w >> 2, wc = w & 3;
  const int row16 = lane & 15, kb = lane >> 4;

  const int lr = lane >> 2, ls = lane & 3;
  const int r0 = (w << 5) + lr, r1 = r0 + 16;
  const unsigned short* pA0 = A  + (size_t)(m0 + r0) * 2048 + ((ls ^ ((r0 >> 1) & 3)) << 3);
  const unsigned short* pA1 = A  + (size_t)(m0 + r1) * 2048 + ((ls ^ ((r1 >> 1) & 3)) << 3);
  const unsigned short* pB0 = Bw + (size_t)(n0 + r0) * 2048 + ((ls ^ ((r0 >> 1) & 3)) << 3);
  const unsigned short* pB1 = Bw + (size_t)(n0 + r1) * 2048 + ((ls ^ ((r1 >> 1) & 3)) << 3);
  const int dW = w << 11;

  f32x4 acc[8][4];
  #pragma unroll
  for (int i = 0; i < 8; ++i)
    #pragma unroll
    for (int j = 0; j < 4; ++j) acc[i][j] = (f32x4){0.f, 0.f, 0.f, 0.f};

  auto STAGE_A = [&](int t) {
    char* base = lds + ((t & 3) << 15);
    const int k0 = t << 5;
    glds16(pA0 + k0, base + dW);
    glds16(pA1 + k0, base + dW + 1024);
  };
  auto STAGE_B = [&](int t) {
    char* base = lds + ((t & 3) << 15);
    const int k0 = t << 5;
    glds16(pB0 + k0, base + 16384 + dW);
    glds16(pB1 + k0, base + 16384 + dW + 1024);
  };
  auto LDA4 = [&](const char* base, int i0, bf16x8 (&af)[4]) {
    #pragma unroll
    for (int i = 0; i < 4; ++i) {
      const int r = (wr << 7) + ((i0 + i) << 4) + row16;
      af[i] = *(const bf16x8*)(base + (r << 6) + ((kb ^ ((r >> 1) & 3)) << 4));
    }
  };
  auto LDB4 = [&](const char* base, bf16x8 (&bfr)[4]) {
    #pragma unroll
    for (int j = 0; j < 4; ++j) {
      const int r = (wc << 6) + (j << 4) + row16;
      bfr[j] = *(const bf16x8*)(base + 16384 + (r << 6) + ((kb ^ ((r >> 1) & 3)) << 4));
    }
  };
  auto MM16 = [&](const bf16x8 (&af)[4], const bf16x8 (&bfr)[4], int i0) {
    #pragma unroll
    for (int i = 0; i < 4; ++i)
      #pragma unroll
      for (int j = 0; j < 4; ++j)
        acc[i0 + i][j] = __builtin_amdgcn_mfma_f32_16x16x32_bf16(af[i], bfr[j], acc[i0 + i][j], 0, 0, 0);
  };
  auto COMPUTE = [&](int t) {
    const char* base = lds + ((t & 3) << 15);
    bf16x8 af[4], af2[4], bfr[4];
    LDA4(base, 0, af); LDA4(base, 4, af2); LDB4(base, bfr);
    MM16(af, bfr, 0); MM16(af2, bfr, 4);
  };

  STAGE_A(0); STAGE_B(0); STAGE_A(1); STAGE_B(1); STAGE_A(2); STAGE_B(2);
  asm volatile("s_waitcnt vmcnt(8)" ::: "memory");
  __builtin_amdgcn_s_barrier();
  __builtin_amdgcn_sched_barrier(0);

  for (int t = 0; t < 61; ++t) {
    const char* base = lds + ((t & 3) << 15);
    bf16x8 af[4], bfr[4];
    LDA4(base, 0, af);
    LDB4(base, bfr);
    STAGE_A(t + 3);
    asm volatile("s_waitcnt lgkmcnt(0)" ::: "memory");
    __builtin_amdgcn_sched_barrier(0);
    __builtin_amdgcn_s_setprio(1);
    MM16(af, bfr, 0);
    __builtin_amdgcn_s_setprio(0);
    __builtin_amdgcn_s_barrier();
    bf16x8 af2[4];
    LDA4(base, 4, af2);
    STAGE_B(t + 3);
    asm volatile("s_waitcnt lgkmcnt(0)" ::: "memory");
    __builtin_amdgcn_sched_barrier(0);
    __builtin_amdgcn_s_setprio(1);
    MM16(af2, bfr, 4);
    __builtin_amdgcn_s_setprio(0);
    asm volatile("s_waitcnt vmcnt(8)" ::: "memory");
    __builtin_amdgcn_s_barrier();
    __builtin_amdgcn_sched_barrier(0);
  }
  COMPUTE(61);
  asm volatile("s_waitcnt vmcnt(4)" ::: "memory");
  __builtin_amdgcn_s_barrier();
  __builtin_amdgcn_sched_barrier(0);
  COMPUTE(62);
  asm volatile("s_waitcnt vmcnt(0)" ::: "memory");
  __builtin_amdgcn_s_barrier();
  __builtin_amdgcn_sched_barrier(0);
  COMPUTE(63);

  const int rq = lane >> 4;
  #pragma unroll
  for (int j = 0; j < 4; ++j) {
    const int oc = n0 + (wc << 6) + (j << 4) + row16;
    const float bj = bias[oc];
    #pragma unroll
    for (int i = 0; i < 8; ++i) {
      const int mr = m0 + (wr << 7) + (i << 4) + (rq << 2);
      #pragma unroll
      for (int q = 0; q < 4; ++q)
        C[(size_t)(mr + q) * 2048 + oc] = acc[i][j][q] + bj;
    }
  }
}

extern "C" void kernel_launch(void* const* d_in, const int* in_sizes, int n_in,
                              void* d_out, int out_size, void* d_ws, size_t ws_size,
                              hipStream_t stream) {
  const float* x  = (const float*)d_in[0];
  const float* gr = (const float*)d_in[1];
  const float* gi = (const float*)d_in[2];
  const float* W  = (const float*)d_in[3];
  const float* bs = (const float*)d_in[4];
  float* out = (float*)d_out;

  char* ws = (char*)d_ws;
  unsigned short* yb = (unsigned short*)ws;                          // 64 MB  y bf16 [b,s,h]
  unsigned short* Wb = (unsigned short*)(ws + (64ull << 20));        // 8 MB   W bf16
  unsigned int*   gt = (unsigned int*)(ws + (72ull << 20));          // 16 MB  gate (fallback)
  uint2*          ab = (uint2*)(ws + (72ull << 20));                 // 16 MB  A/B table (fast)
  unsigned short* xT = (unsigned short*)(ws + (88ull << 20));        // 64 MB  x transposed BF16 [b,h,s]
  unsigned short* yT = (unsigned short*)(ws + (216ull << 20));       // 64 MB  y transposed [b,h,s]
  const bool fast = ws_size >= (280ull << 20);

  hipLaunchKernelGGL(wconv_k, dim3(4096), dim3(256), 0, stream, W, Wb);
  if (fast) {
    hipLaunchKernelGGL(gate_ab_k, dim3(32, 64), dim3(256), 0, stream, gr, gi, ab);
    hipLaunchKernelGGL(xtrans_k, dim3(32, 32, 8), dim3(256), 0, stream, x, xT);
    hipLaunchKernelGGL(fftr_k, dim3(4096), dim3(256), 0, stream, xT, ab, yT);
    hipLaunchKernelGGL(ytrans_k, dim3(32, 32, 8), dim3(256), 0, stream, yT, yb);
  } else {
    hipLaunchKernelGGL(gate_pack_k, dim3(64, 64), dim3(256), 0, stream, gr, gi, gt);
    hipLaunchKernelGGL(fft_gate_k, dim3(2048), dim3(512), 0, stream, x, gt, yb);
  }

  const bool big = hipFuncSetAttribute((const void*)gemm8_k,
                                       hipFuncAttributeMaxDynamicSharedMemorySize,
                                       131072) == hipSuccess;
  if (big) {
    hipLaunchKernelGGL(gemm8_k, dim3(512), dim3(512), 131072, stream, yb, Wb, bs, out);
  } else {
    hipLaunchKernelGGL(gemm_k, dim3(2048), dim3(256), 0, stream, yb, Wb, bs, out);
  }
}